// Round 2
// baseline (1153.299 us; speedup 1.0000x reference)
//
#include <hip/hip_runtime.h>
#include <math.h>

#define NN 100000
#define NE 800000
#define F_IN 128
#define CH 32
#define NC 16
#define CSTF 1e-5f

// ---------------- utility ---------------------------------------------------
__global__ void zero_kernel(int* __restrict__ p, int n) {
    int i = blockIdx.x * 256 + threadIdx.x;
    if (i < n) p[i] = 0;
}

// ---------------- edge dtype detection (int32 vs int64 storage) -------------
__global__ void detect_kernel(const int* __restrict__ ei, int* __restrict__ mode) {
    __shared__ int any_nz;
    if (threadIdx.x == 0) any_nz = 0;
    __syncthreads();
    int nz = 0;
    for (int i = threadIdx.x; i < 4096; i += 256) nz |= (ei[2 * i + 1] != 0);
    if (nz) atomicOr(&any_nz, 1);
    __syncthreads();
    if (threadIdx.x == 0) *mode = any_nz ? 0 : 1;   // 1 => int64 storage
}

__device__ __forceinline__ int get_row(const int* ei, int e, int m) {
    return m ? ei[2 * e] : ei[e];
}
__device__ __forceinline__ int get_col(const int* ei, int e, int m) {
    return m ? ei[2 * NE + 2 * e] : ei[NE + e];
}

// ---------------- CSR build -------------------------------------------------
__global__ void count_kernel(const int* __restrict__ ei, int* __restrict__ deg,
                             const int* __restrict__ mode) {
    int e = blockIdx.x * 256 + threadIdx.x;
    int m = *mode;
    if (e < NE) atomicAdd(&deg[get_col(ei, e, m)], 1);
}

__global__ void scan1_kernel(const int* __restrict__ deg, int* __restrict__ offs,
                             int* __restrict__ bsums) {
    __shared__ int sd[256];
    int tid = threadIdx.x;
    int base = blockIdx.x * 1024 + tid * 4;
    int v[4]; int s = 0;
#pragma unroll
    for (int k = 0; k < 4; ++k) { v[k] = (base + k < NN) ? deg[base + k] : 0; s += v[k]; }
    sd[tid] = s;
    __syncthreads();
    for (int off = 1; off < 256; off <<= 1) {
        int t = (tid >= off) ? sd[tid - off] : 0;
        __syncthreads();
        sd[tid] += t;
        __syncthreads();
    }
    int excl = sd[tid] - s;
    if (tid == 255) bsums[blockIdx.x] = sd[255];
    int p = excl;
#pragma unroll
    for (int k = 0; k < 4; ++k) {
        if (base + k < NN) offs[base + k] = p;
        p += v[k];
    }
}

__global__ void scan2_kernel(int* __restrict__ bsums, int nb) {
    __shared__ int sd[128];
    int tid = threadIdx.x;
    int v = (tid < nb) ? bsums[tid] : 0;
    sd[tid] = v;
    __syncthreads();
    for (int off = 1; off < 128; off <<= 1) {
        int t = (tid >= off) ? sd[tid - off] : 0;
        __syncthreads();
        sd[tid] += t;
        __syncthreads();
    }
    if (tid < nb) bsums[tid] = sd[tid] - v;   // exclusive
}

__global__ void scan3_kernel(int* __restrict__ offs, const int* __restrict__ bsums,
                             int* __restrict__ cursor) {
    int i = blockIdx.x * 256 + threadIdx.x;
    if (i < NN) {
        int o = offs[i] + bsums[i >> 10];
        offs[i] = o;
        cursor[i] = o;
    }
    if (i == 0) offs[NN] = NE;
}

__global__ void fill_kernel(const int* __restrict__ ei, int* __restrict__ cursor,
                            int* __restrict__ srcs, const int* __restrict__ mode) {
    int e = blockIdx.x * 256 + threadIdx.x;
    int m = *mode;
    if (e < NE) {
        int c = get_col(ei, e, m);
        int p = atomicAdd(&cursor[c], 1);
        srcs[p] = get_row(ei, e, m);
    }
}

// ---------------- phase 1: per-node MLPs, write Q,K,V and out=hw0*V ---------
__global__ __launch_bounds__(256) void phase1_kernel(
    const float* __restrict__ feat, const float* __restrict__ Win,
    const float* __restrict__ bin, const float* __restrict__ Wq,
    const float* __restrict__ bq, const float* __restrict__ Wk,
    const float* __restrict__ bk, const float* __restrict__ Wv,
    const float* __restrict__ bv, const float* __restrict__ hopwise,
    float* __restrict__ Qg, float* __restrict__ Kg, float* __restrict__ Vg,
    float* __restrict__ out)
{
    __shared__ float sWin[F_IN * CH];
    __shared__ float sWq[CH * CH];
    __shared__ float sWk[CH * CH];
    __shared__ float sWv[CH * NC];
    __shared__ float sbin[CH], sbq[CH], sbk[CH], sbv[NC];

    int tid = threadIdx.x;
    for (int i = tid; i < F_IN * CH; i += 256) sWin[i] = Win[i];
    for (int i = tid; i < CH * CH; i += 256) { sWq[i] = Wq[i]; sWk[i] = Wk[i]; }
    for (int i = tid; i < CH * NC; i += 256) sWv[i] = Wv[i];
    if (tid < CH) { sbin[tid] = bin[tid]; sbq[tid] = bq[tid]; sbk[tid] = bk[tid]; }
    if (tid < NC) sbv[tid] = bv[tid];
    __syncthreads();

    int wid  = tid >> 6;
    int lane = tid & 63;
    int half = lane >> 5;
    int c    = lane & 31;
    int node = (blockIdx.x * 4 + wid) * 2 + half;
    bool valid = node < NN;

    float x = 0.f;
    if (valid) {
        const float4* f4 = (const float4*)(feat + (size_t)node * F_IN);
#pragma unroll
        for (int t = 0; t < F_IN / 4; ++t) {
            float4 fv = f4[t];
            x += fv.x * sWin[(4 * t + 0) * CH + c];
            x += fv.y * sWin[(4 * t + 1) * CH + c];
            x += fv.z * sWin[(4 * t + 2) * CH + c];
            x += fv.w * sWin[(4 * t + 3) * CH + c];
        }
        x += sbin[c];
        x = fmaxf(x, 0.f);
    }

    float q = 0.f, k = 0.f, v = 0.f;
#pragma unroll
    for (int j = 0; j < CH; ++j) {
        float xj = __shfl(x, j, 32);
        q += xj * sWq[j * CH + c];
        k += xj * sWk[j * CH + c];
        if (c < NC) v += xj * sWv[j * NC + c];
    }
    q += sbq[c]; q = 1.f + ((q > 0.f) ? q : (expf(q) - 1.f));
    k += sbk[c]; k = 1.f + ((k > 0.f) ? k : (expf(k) - 1.f));

    if (valid) {
        Qg[(size_t)node * CH + c] = q;
        Kg[(size_t)node * CH + c] = k;
        if (c < NC) {
            float vv = v + sbv[c];
            Vg[(size_t)node * NC + c] = vv;
            out[(size_t)node * NC + c] = hopwise[0] * vv;
        }
    }
}

// ---------------- K propagation + sc_h = hopwise[h]/(Q·K_h + CST) -----------
__global__ __launch_bounds__(256) void kprop_kernel(
    const float* __restrict__ Qg, const float* __restrict__ Kin,
    float* __restrict__ Kout, const int* __restrict__ offs,
    const int* __restrict__ srcs, const float* __restrict__ hopw, int hop,
    float* __restrict__ sc)
{
    int tid = threadIdx.x;
    int wid = tid >> 6, lane = tid & 63;
    int half = lane >> 5, c = lane & 31;
    int node = blockIdx.x * 8 + wid * 2 + half;
    if (node >= NN) return;

    float k = 0.f;
    int s = offs[node], e = offs[node + 1];
    for (int i = s; i < e; ++i) k += Kin[(size_t)srcs[i] * CH + c];
    Kout[(size_t)node * CH + c] = k;

    float cp = Qg[(size_t)node * CH + c] * k;
#pragma unroll
    for (int m = 1; m < 32; m <<= 1) cp += __shfl_xor(cp, m, 32);
    if (c == 0) sc[node] = hopw[hop] / (cp + CSTF);
}

// ---------------- chunked hop over M columns --------------------------------
// Chunk layout per node: [CB rows of c][16 cols of j], flat f = e*64 + lane,
// j = lane&15 (invariant per lane), c = e*4 + (lane>>4).
template<int CB, bool RANK1, bool WRITE>
__global__ __launch_bounds__(256) void hopc_kernel(
    const float* __restrict__ Qg, const float* __restrict__ K0,
    const float* __restrict__ Vg, const float* __restrict__ Min,
    float* __restrict__ Mout, const int* __restrict__ offs,
    const int* __restrict__ srcs, const float* __restrict__ sc,
    int c0, float* __restrict__ out)
{
    constexpr int EPL = CB * 16 / 64;   // elems per lane (CB>=4)
    int tid = threadIdx.x;
    int wid = tid >> 6, lane = tid & 63;
    int node = blockIdx.x * 4 + wid;
    if (node >= NN) return;

    float acc[EPL];
#pragma unroll
    for (int k = 0; k < EPL; ++k) acc[k] = 0.f;

    int s = offs[node], e = offs[node + 1];
    int j = lane & 15;
    int crow = lane >> 4;

    for (int i = s; i < e; ++i) {
        int src = srcs[i];
        if (RANK1) {
            float vj = Vg[(size_t)src * NC + j];
            const float* krow = K0 + (size_t)src * CH + c0;
#pragma unroll
            for (int k = 0; k < EPL; ++k) acc[k] += krow[k * 4 + crow] * vj;
        } else {
            const float* mrow = Min + (size_t)src * (CB * 16);
#pragma unroll
            for (int k = 0; k < EPL; ++k) acc[k] += mrow[k * 64 + lane];
        }
    }

    if (WRITE) {
        float* mo = Mout + (size_t)node * (CB * 16);
#pragma unroll
        for (int k = 0; k < EPL; ++k) mo[k * 64 + lane] = acc[k];
    }

    const float* q = Qg + (size_t)node * CH + c0;
    float h = 0.f;
#pragma unroll
    for (int k = 0; k < EPL; ++k) h += q[k * 4 + crow] * acc[k];
    h += __shfl_xor(h, 16);
    h += __shfl_xor(h, 32);

    if (lane < 16) out[(size_t)node * NC + lane] += sc[node] * h;
}

template<int CB>
static void run_chunks(const float* Qg, const float* K0, const float* Vg,
                       float* MA, float* MB, const int* offs, const int* srcs,
                       const float* sc1, const float* sc2, const float* sc3,
                       float* out, hipStream_t stream)
{
    for (int c0 = 0; c0 < CH; c0 += CB) {
        hopc_kernel<CB, true,  true ><<<25000, 256, 0, stream>>>(Qg, K0, Vg, nullptr, MA, offs, srcs, sc1, c0, out);
        hopc_kernel<CB, false, true ><<<25000, 256, 0, stream>>>(Qg, K0, Vg, MA, MB, offs, srcs, sc2, c0, out);
        hopc_kernel<CB, false, false><<<25000, 256, 0, stream>>>(Qg, K0, Vg, MB, nullptr, offs, srcs, sc3, c0, out);
    }
}

// ---------------- launch ----------------------------------------------------
extern "C" void kernel_launch(void* const* d_in, const int* in_sizes, int n_in,
                              void* d_out, int out_size, void* d_ws, size_t ws_size,
                              hipStream_t stream) {
    const float* feat = (const float*)d_in[0];
    const int*   ei   = (const int*)d_in[1];
    const float* Win  = (const float*)d_in[2];
    const float* bin  = (const float*)d_in[3];
    const float* Wq   = (const float*)d_in[4];
    const float* bq   = (const float*)d_in[5];
    const float* Wk   = (const float*)d_in[6];
    const float* bk   = (const float*)d_in[7];
    const float* Wv   = (const float*)d_in[8];
    const float* bv   = (const float*)d_in[9];
    const float* hopw = (const float*)d_in[10];
    float* out = (float*)d_out;

    char* ws = (char*)d_ws;
    size_t off = 0;
    auto alloc = [&](size_t bytes) -> void* {
        void* p = ws + off;
        off += (bytes + 255) & ~(size_t)255;
        return p;
    };
    float* Qg  = (float*)alloc((size_t)NN * CH * 4);
    float* K0  = (float*)alloc((size_t)NN * CH * 4);
    float* Ka  = (float*)alloc((size_t)NN * CH * 4);
    float* Kb  = (float*)alloc((size_t)NN * CH * 4);
    float* Vg  = (float*)alloc((size_t)NN * NC * 4);
    float* sc1 = (float*)alloc((size_t)NN * 4);
    float* sc2 = (float*)alloc((size_t)NN * 4);
    float* sc3 = (float*)alloc((size_t)NN * 4);
    int*   deg = (int*)alloc((size_t)NN * 4);
    int*   offs   = (int*)alloc((size_t)(NN + 1) * 4);
    int*   cursor = (int*)alloc((size_t)NN * 4);
    int*   bsums  = (int*)alloc(512);
    int*   mode   = (int*)alloc(4);
    int*   srcs   = (int*)alloc((size_t)NE * 4);
    size_t fixed = off;

    // pick largest chunk width whose ping-pong fits in the remaining ws
    auto mbytes = [](int cb) { return (size_t)NN * cb * 16 * 4; };
    int CB = 4;
    if      (ws_size >= fixed + 2 * mbytes(32) + 512) CB = 32;
    else if (ws_size >= fixed + 2 * mbytes(16) + 512) CB = 16;
    else if (ws_size >= fixed + 2 * mbytes(8)  + 512) CB = 8;
    float* MA = (float*)alloc(mbytes(CB));
    float* MB = (float*)alloc(mbytes(CB));

    // CSR build
    zero_kernel<<<(NN + 255) / 256, 256, 0, stream>>>(deg, NN);
    detect_kernel<<<1, 256, 0, stream>>>(ei, mode);
    count_kernel<<<(NE + 255) / 256, 256, 0, stream>>>(ei, deg, mode);
    int nb = (NN + 1023) / 1024;
    scan1_kernel<<<nb, 256, 0, stream>>>(deg, offs, bsums);
    scan2_kernel<<<1, 128, 0, stream>>>(bsums, nb);
    scan3_kernel<<<(NN + 255) / 256, 256, 0, stream>>>(offs, bsums, cursor);
    fill_kernel<<<(NE + 255) / 256, 256, 0, stream>>>(ei, cursor, srcs, mode);

    // node-wise MLPs
    phase1_kernel<<<12500, 256, 0, stream>>>(feat, Win, bin, Wq, bq, Wk, bk, Wv, bv,
                                             hopw, Qg, K0, Vg, out);

    // K propagation + per-hop scale factors
    kprop_kernel<<<12500, 256, 0, stream>>>(Qg, K0, Ka, offs, srcs, hopw, 1, sc1);
    kprop_kernel<<<12500, 256, 0, stream>>>(Qg, Ka, Kb, offs, srcs, hopw, 2, sc2);
    kprop_kernel<<<12500, 256, 0, stream>>>(Qg, Kb, Ka, offs, srcs, hopw, 3, sc3);

    // chunked M propagation with fused readout
    if      (CB == 32) run_chunks<32>(Qg, K0, Vg, MA, MB, offs, srcs, sc1, sc2, sc3, out, stream);
    else if (CB == 16) run_chunks<16>(Qg, K0, Vg, MA, MB, offs, srcs, sc1, sc2, sc3, out, stream);
    else if (CB == 8)  run_chunks<8> (Qg, K0, Vg, MA, MB, offs, srcs, sc1, sc2, sc3, out, stream);
    else               run_chunks<4> (Qg, K0, Vg, MA, MB, offs, srcs, sc1, sc2, sc3, out, stream);
}

// Round 4
// 824.707 us; speedup vs baseline: 1.3984x; 1.3984x over previous
//
#include <hip/hip_runtime.h>
#include <math.h>

#define NN 100000
#define NE 800000
#define F_IN 128
#define CH 32
#define NC 16
#define CSTF 1e-5f

// ---------------- bf16 helpers ----------------------------------------------
__device__ __forceinline__ float bf_lo(unsigned int u) {
    unsigned int t = u << 16;
    return __builtin_bit_cast(float, t);
}
__device__ __forceinline__ float bf_hi(unsigned int u) {
    unsigned int t = u & 0xffff0000u;
    return __builtin_bit_cast(float, t);
}
__device__ __forceinline__ unsigned int bf_round(float a) {
    unsigned int ua = __builtin_bit_cast(unsigned int, a);
    return (ua + 0x7fffu + ((ua >> 16) & 1u)) >> 16;     // RNE, a is finite
}
__device__ __forceinline__ unsigned int pack_bf(float a, float b) {
    return bf_round(a) | (bf_round(b) << 16);
}

// ---------------- utility ---------------------------------------------------
__global__ void zero_kernel(int* __restrict__ p, int n) {
    int i = blockIdx.x * 256 + threadIdx.x;
    if (i < n) p[i] = 0;
}

// ---------------- edge dtype detection (int32 vs int64 storage) -------------
__global__ void detect_kernel(const int* __restrict__ ei, int* __restrict__ mode) {
    __shared__ int any_nz;
    if (threadIdx.x == 0) any_nz = 0;
    __syncthreads();
    int nz = 0;
    for (int i = threadIdx.x; i < 4096; i += 256) nz |= (ei[2 * i + 1] != 0);
    if (nz) atomicOr(&any_nz, 1);
    __syncthreads();
    if (threadIdx.x == 0) *mode = any_nz ? 0 : 1;   // 1 => int64 storage
}

__device__ __forceinline__ int get_row(const int* ei, int e, int m) {
    return m ? ei[2 * e] : ei[e];
}
__device__ __forceinline__ int get_col(const int* ei, int e, int m) {
    return m ? ei[2 * NE + 2 * e] : ei[NE + e];
}

// ---------------- CSR build -------------------------------------------------
__global__ void count_kernel(const int* __restrict__ ei, int* __restrict__ deg,
                             const int* __restrict__ mode) {
    int e = blockIdx.x * 256 + threadIdx.x;
    int m = *mode;
    if (e < NE) atomicAdd(&deg[get_col(ei, e, m)], 1);
}

__global__ void scan1_kernel(const int* __restrict__ deg, int* __restrict__ offs,
                             int* __restrict__ bsums) {
    __shared__ int sd[256];
    int tid = threadIdx.x;
    int base = blockIdx.x * 1024 + tid * 4;
    int v[4]; int s = 0;
#pragma unroll
    for (int k = 0; k < 4; ++k) { v[k] = (base + k < NN) ? deg[base + k] : 0; s += v[k]; }
    sd[tid] = s;
    __syncthreads();
    for (int off = 1; off < 256; off <<= 1) {
        int t = (tid >= off) ? sd[tid - off] : 0;
        __syncthreads();
        sd[tid] += t;
        __syncthreads();
    }
    int excl = sd[tid] - s;
    if (tid == 255) bsums[blockIdx.x] = sd[255];
    int p = excl;
#pragma unroll
    for (int k = 0; k < 4; ++k) {
        if (base + k < NN) offs[base + k] = p;
        p += v[k];
    }
}

__global__ void scan2_kernel(int* __restrict__ bsums, int nb) {
    __shared__ int sd[128];
    int tid = threadIdx.x;
    int v = (tid < nb) ? bsums[tid] : 0;
    sd[tid] = v;
    __syncthreads();
    for (int off = 1; off < 128; off <<= 1) {
        int t = (tid >= off) ? sd[tid - off] : 0;
        __syncthreads();
        sd[tid] += t;
        __syncthreads();
    }
    if (tid < nb) bsums[tid] = sd[tid] - v;   // exclusive
}

__global__ void scan3_kernel(int* __restrict__ offs, const int* __restrict__ bsums,
                             int* __restrict__ cursor) {
    int i = blockIdx.x * 256 + threadIdx.x;
    if (i < NN) {
        int o = offs[i] + bsums[i >> 10];
        offs[i] = o;
        cursor[i] = o;
    }
    if (i == 0) offs[NN] = NE;
}

__global__ void fill_kernel(const int* __restrict__ ei, int* __restrict__ cursor,
                            int* __restrict__ srcs, const int* __restrict__ mode) {
    int e = blockIdx.x * 256 + threadIdx.x;
    int m = *mode;
    if (e < NE) {
        int c = get_col(ei, e, m);
        int p = atomicAdd(&cursor[c], 1);
        srcs[p] = get_row(ei, e, m);
    }
}

// ---------------- phase 1: per-node MLPs, write Q,K,V and out=hw0*V ---------
__global__ __launch_bounds__(256) void phase1_kernel(
    const float* __restrict__ feat, const float* __restrict__ Win,
    const float* __restrict__ bin, const float* __restrict__ Wq,
    const float* __restrict__ bq, const float* __restrict__ Wk,
    const float* __restrict__ bk, const float* __restrict__ Wv,
    const float* __restrict__ bv, const float* __restrict__ hopwise,
    float* __restrict__ Qg, float* __restrict__ Kg, float* __restrict__ Vg,
    float* __restrict__ out)
{
    __shared__ float sWin[F_IN * CH];
    __shared__ float sWq[CH * CH];
    __shared__ float sWk[CH * CH];
    __shared__ float sWv[CH * NC];
    __shared__ float sbin[CH], sbq[CH], sbk[CH], sbv[NC];

    int tid = threadIdx.x;
    for (int i = tid; i < F_IN * CH; i += 256) sWin[i] = Win[i];
    for (int i = tid; i < CH * CH; i += 256) { sWq[i] = Wq[i]; sWk[i] = Wk[i]; }
    for (int i = tid; i < CH * NC; i += 256) sWv[i] = Wv[i];
    if (tid < CH) { sbin[tid] = bin[tid]; sbq[tid] = bq[tid]; sbk[tid] = bk[tid]; }
    if (tid < NC) sbv[tid] = bv[tid];
    __syncthreads();

    int wid  = tid >> 6;
    int lane = tid & 63;
    int half = lane >> 5;
    int c    = lane & 31;
    int node = (blockIdx.x * 4 + wid) * 2 + half;
    bool valid = node < NN;

    float x = 0.f;
    if (valid) {
        const float4* f4 = (const float4*)(feat + (size_t)node * F_IN);
#pragma unroll
        for (int t = 0; t < F_IN / 4; ++t) {
            float4 fv = f4[t];
            x += fv.x * sWin[(4 * t + 0) * CH + c];
            x += fv.y * sWin[(4 * t + 1) * CH + c];
            x += fv.z * sWin[(4 * t + 2) * CH + c];
            x += fv.w * sWin[(4 * t + 3) * CH + c];
        }
        x += sbin[c];
        x = fmaxf(x, 0.f);
    }

    float q = 0.f, k = 0.f, v = 0.f;
#pragma unroll
    for (int j = 0; j < CH; ++j) {
        float xj = __shfl(x, j, 32);
        q += xj * sWq[j * CH + c];
        k += xj * sWk[j * CH + c];
        if (c < NC) v += xj * sWv[j * NC + c];
    }
    q += sbq[c]; q = 1.f + ((q > 0.f) ? q : (expf(q) - 1.f));
    k += sbk[c]; k = 1.f + ((k > 0.f) ? k : (expf(k) - 1.f));

    if (valid) {
        Qg[(size_t)node * CH + c] = q;
        Kg[(size_t)node * CH + c] = k;
        if (c < NC) {
            float vv = v + sbv[c];
            Vg[(size_t)node * NC + c] = vv;
            out[(size_t)node * NC + c] = hopwise[0] * vv;
        }
    }
}

// ---------------- K propagation + sc_h = hopwise[h]/(Q·K_h + CST) -----------
__global__ __launch_bounds__(256) void kprop_kernel(
    const float* __restrict__ Qg, const float* __restrict__ Kin,
    float* __restrict__ Kout, const int* __restrict__ offs,
    const int* __restrict__ srcs, const float* __restrict__ hopw, int hop,
    float* __restrict__ sc)
{
    int tid = threadIdx.x;
    int wid = tid >> 6, lane = tid & 63;
    int half = lane >> 5, c = lane & 31;
    int node = blockIdx.x * 8 + wid * 2 + half;
    if (node >= NN) return;

    float k = 0.f;
    int s = offs[node], e = offs[node + 1];
    for (int i = s; i < e; ++i) k += Kin[(size_t)srcs[i] * CH + c];
    Kout[(size_t)node * CH + c] = k;

    float cp = Qg[(size_t)node * CH + c] * k;
#pragma unroll
    for (int m = 1; m < 32; m <<= 1) cp += __shfl_xor(cp, m, 32);
    if (c == 0) sc[node] = hopw[hop] / (cp + CSTF);
}

// ---------------- chunked hop over M columns (bf16 M storage) ---------------
// M chunk row per node: CB*16 bf16 values. Element f = lane*EPL + k,
// c = c0 + lane/L, j = EPL*(lane&(L-1)) + k, where EPL=CB*16/64, L=16/EPL.
template<int CB, bool RANK1, bool WRITE>
__global__ __launch_bounds__(256) void hopc_kernel(
    const float* __restrict__ Qg, const float* __restrict__ K0,
    const float* __restrict__ Vg, const unsigned short* __restrict__ Min,
    unsigned short* __restrict__ Mout, const int* __restrict__ offs,
    const int* __restrict__ srcs, const float* __restrict__ sc,
    int c0, float* __restrict__ out)
{
    constexpr int EPL = CB * 16 / 64;     // 8, 4, 2, 1
    constexpr int L   = 16 / EPL;         // lanes covering one c-row
    int tid = threadIdx.x;
    int wid = tid >> 6, lane = tid & 63;
    int node = blockIdx.x * 4 + wid;
    if (node >= NN) return;

    int jb = EPL * (lane & (L - 1));
    int cl = lane / L;                    // 0..CB-1

    float acc[EPL];
#pragma unroll
    for (int k = 0; k < EPL; ++k) acc[k] = 0.f;

    int s = offs[node], e = offs[node + 1];
    for (int i = s; i < e; ++i) {
        int src = srcs[i];
        if (RANK1) {
            float kc = K0[(size_t)src * CH + c0 + cl];
            const float* vp = Vg + (size_t)src * NC + jb;
            if (EPL == 8) {
                float4 a = *(const float4*)vp;
                float4 b = *(const float4*)(vp + 4);
                acc[0] += kc * a.x; acc[1] += kc * a.y;
                acc[2] += kc * a.z; acc[3] += kc * a.w;
                acc[4] += kc * b.x; acc[5] += kc * b.y;
                acc[6] += kc * b.z; acc[7] += kc * b.w;
            } else if (EPL == 4) {
                float4 a = *(const float4*)vp;
                acc[0] += kc * a.x; acc[1] += kc * a.y;
                acc[2] += kc * a.z; acc[3] += kc * a.w;
            } else if (EPL == 2) {
                float2 a = *(const float2*)vp;
                acc[0] += kc * a.x; acc[1] += kc * a.y;
            } else {
                acc[0] += kc * vp[0];
            }
        } else {
            const unsigned short* mi = Min + (size_t)src * (CB * 16) + lane * EPL;
            if (EPL == 8) {
                uint4 u = *(const uint4*)mi;
                acc[0] += bf_lo(u.x); acc[1] += bf_hi(u.x);
                acc[2] += bf_lo(u.y); acc[3] += bf_hi(u.y);
                acc[4] += bf_lo(u.z); acc[5] += bf_hi(u.z);
                acc[6] += bf_lo(u.w); acc[7] += bf_hi(u.w);
            } else if (EPL == 4) {
                uint2 u = *(const uint2*)mi;
                acc[0] += bf_lo(u.x); acc[1] += bf_hi(u.x);
                acc[2] += bf_lo(u.y); acc[3] += bf_hi(u.y);
            } else if (EPL == 2) {
                unsigned int u = *(const unsigned int*)mi;
                acc[0] += bf_lo(u); acc[1] += bf_hi(u);
            } else {
                unsigned int u = *mi;
                acc[0] += bf_lo(u << 16) * 0.f + bf_lo(u); // u is 16-bit value
            }
        }
    }

    if (WRITE) {
        unsigned short* mo = Mout + (size_t)node * (CB * 16) + lane * EPL;
        if (EPL == 8) {
            uint4 u;
            u.x = pack_bf(acc[0], acc[1]);
            u.y = pack_bf(acc[2], acc[3]);
            u.z = pack_bf(acc[4], acc[5]);
            u.w = pack_bf(acc[6], acc[7]);
            *(uint4*)mo = u;
        } else if (EPL == 4) {
            uint2 u;
            u.x = pack_bf(acc[0], acc[1]);
            u.y = pack_bf(acc[2], acc[3]);
            *(uint2*)mo = u;
        } else if (EPL == 2) {
            *(unsigned int*)mo = pack_bf(acc[0], acc[1]);
        } else {
            *mo = (unsigned short)bf_round(acc[0]);
        }
    }

    // readout: H[j] = sum_c Q[c] * M[c,j], then out += sc * H
    float q = Qg[(size_t)node * CH + c0 + cl];
    float h[EPL];
#pragma unroll
    for (int k = 0; k < EPL; ++k) h[k] = q * acc[k];
#pragma unroll
    for (int st = L; st < 64; st <<= 1) {
#pragma unroll
        for (int k = 0; k < EPL; ++k) h[k] += __shfl_xor(h[k], st);
    }
    if (lane < L) {
        float scn = sc[node];
#pragma unroll
        for (int k = 0; k < EPL; ++k)
            out[(size_t)node * NC + jb + k] += scn * h[k];
    }
}

template<int CB>
static void run_chunks(const float* Qg, const float* K0, const float* Vg,
                       unsigned short* MA, unsigned short* MB,
                       const int* offs, const int* srcs,
                       const float* sc1, const float* sc2, const float* sc3,
                       float* out, hipStream_t stream)
{
    for (int c0 = 0; c0 < CH; c0 += CB) {
        hopc_kernel<CB, true,  true ><<<25000, 256, 0, stream>>>(Qg, K0, Vg, nullptr, MA, offs, srcs, sc1, c0, out);
        hopc_kernel<CB, false, true ><<<25000, 256, 0, stream>>>(Qg, K0, Vg, MA, MB, offs, srcs, sc2, c0, out);
        hopc_kernel<CB, false, false><<<25000, 256, 0, stream>>>(Qg, K0, Vg, MB, nullptr, offs, srcs, sc3, c0, out);
    }
}

// ---------------- launch ----------------------------------------------------
extern "C" void kernel_launch(void* const* d_in, const int* in_sizes, int n_in,
                              void* d_out, int out_size, void* d_ws, size_t ws_size,
                              hipStream_t stream) {
    const float* feat = (const float*)d_in[0];
    const int*   ei   = (const int*)d_in[1];
    const float* Win  = (const float*)d_in[2];
    const float* bin  = (const float*)d_in[3];
    const float* Wq   = (const float*)d_in[4];
    const float* bq   = (const float*)d_in[5];
    const float* Wk   = (const float*)d_in[6];
    const float* bk   = (const float*)d_in[7];
    const float* Wv   = (const float*)d_in[8];
    const float* bv   = (const float*)d_in[9];
    const float* hopw = (const float*)d_in[10];
    float* out = (float*)d_out;

    char* ws = (char*)d_ws;
    size_t off = 0;
    auto alloc = [&](size_t bytes) -> void* {
        void* p = ws + off;
        off += (bytes + 255) & ~(size_t)255;
        return p;
    };
    float* Qg  = (float*)alloc((size_t)NN * CH * 4);
    float* K0  = (float*)alloc((size_t)NN * CH * 4);
    float* Ka  = (float*)alloc((size_t)NN * CH * 4);
    float* Kb  = (float*)alloc((size_t)NN * CH * 4);
    float* Vg  = (float*)alloc((size_t)NN * NC * 4);
    float* sc1 = (float*)alloc((size_t)NN * 4);
    float* sc2 = (float*)alloc((size_t)NN * 4);
    float* sc3 = (float*)alloc((size_t)NN * 4);
    int*   deg = (int*)alloc((size_t)NN * 4);
    int*   offs   = (int*)alloc((size_t)(NN + 1) * 4);
    int*   cursor = (int*)alloc((size_t)NN * 4);
    int*   bsums  = (int*)alloc(512);
    int*   mode   = (int*)alloc(4);
    int*   srcs   = (int*)alloc((size_t)NE * 4);
    size_t fixed = off;

    // bf16 M ping-pong: CB*16*2 bytes per node per buffer
    auto mbytes = [](int cb) { return (size_t)NN * cb * 16 * 2; };
    int CB = 4;
    if      (ws_size >= fixed + 2 * mbytes(32) + 512) CB = 32;
    else if (ws_size >= fixed + 2 * mbytes(16) + 512) CB = 16;
    else if (ws_size >= fixed + 2 * mbytes(8)  + 512) CB = 8;
    unsigned short* MA = (unsigned short*)alloc(mbytes(CB));
    unsigned short* MB = (unsigned short*)alloc(mbytes(CB));

    // CSR build
    zero_kernel<<<(NN + 255) / 256, 256, 0, stream>>>(deg, NN);
    detect_kernel<<<1, 256, 0, stream>>>(ei, mode);
    count_kernel<<<(NE + 255) / 256, 256, 0, stream>>>(ei, deg, mode);
    int nb = (NN + 1023) / 1024;
    scan1_kernel<<<nb, 256, 0, stream>>>(deg, offs, bsums);
    scan2_kernel<<<1, 128, 0, stream>>>(bsums, nb);
    scan3_kernel<<<(NN + 255) / 256, 256, 0, stream>>>(offs, bsums, cursor);
    fill_kernel<<<(NE + 255) / 256, 256, 0, stream>>>(ei, cursor, srcs, mode);

    // node-wise MLPs
    phase1_kernel<<<12500, 256, 0, stream>>>(feat, Win, bin, Wq, bq, Wk, bk, Wv, bv,
                                             hopw, Qg, K0, Vg, out);

    // K propagation + per-hop scale factors
    kprop_kernel<<<12500, 256, 0, stream>>>(Qg, K0, Ka, offs, srcs, hopw, 1, sc1);
    kprop_kernel<<<12500, 256, 0, stream>>>(Qg, Ka, Kb, offs, srcs, hopw, 2, sc2);
    kprop_kernel<<<12500, 256, 0, stream>>>(Qg, Kb, Ka, offs, srcs, hopw, 3, sc3);

    // chunked bf16 M propagation with fused readout
    if      (CB == 32) run_chunks<32>(Qg, K0, Vg, MA, MB, offs, srcs, sc1, sc2, sc3, out, stream);
    else if (CB == 16) run_chunks<16>(Qg, K0, Vg, MA, MB, offs, srcs, sc1, sc2, sc3, out, stream);
    else if (CB == 8)  run_chunks<8> (Qg, K0, Vg, MA, MB, offs, srcs, sc1, sc2, sc3, out, stream);
    else               run_chunks<4> (Qg, K0, Vg, MA, MB, offs, srcs, sc1, sc2, sc3, out, stream);
}

// Round 5
// 629.207 us; speedup vs baseline: 1.8329x; 1.3107x over previous
//
#include <hip/hip_runtime.h>
#include <math.h>

#define NN 100000
#define NE 800000
#define F_IN 128
#define CH 32
#define NC 16
#define CSTF 1e-5f

// ---------------- bf16 helpers ----------------------------------------------
__device__ __forceinline__ float bf_lo(unsigned int u) {
    unsigned int t = u << 16;
    return __builtin_bit_cast(float, t);
}
__device__ __forceinline__ float bf_hi(unsigned int u) {
    unsigned int t = u & 0xffff0000u;
    return __builtin_bit_cast(float, t);
}
__device__ __forceinline__ float bf_val(unsigned short v) {
    unsigned int t = ((unsigned int)v) << 16;
    return __builtin_bit_cast(float, t);
}
__device__ __forceinline__ unsigned int bf_round(float a) {
    unsigned int ua = __builtin_bit_cast(unsigned int, a);
    return (ua + 0x7fffu + ((ua >> 16) & 1u)) >> 16;     // RNE, a finite
}

// fp8 e4m3 clamp: avoid NaN on overflow (max normal = 448)
__device__ __forceinline__ float cl448(float a) {
    return fminf(fmaxf(a, -448.f), 448.f);
}

// ---------------- utility ---------------------------------------------------
__global__ void zero_kernel(int* __restrict__ p, int n) {
    int i = blockIdx.x * 256 + threadIdx.x;
    if (i < n) p[i] = 0;
}

// ---------------- edge dtype detection (int32 vs int64 storage) -------------
__global__ void detect_kernel(const int* __restrict__ ei, int* __restrict__ mode) {
    __shared__ int any_nz;
    if (threadIdx.x == 0) any_nz = 0;
    __syncthreads();
    int nz = 0;
    for (int i = threadIdx.x; i < 4096; i += 256) nz |= (ei[2 * i + 1] != 0);
    if (nz) atomicOr(&any_nz, 1);
    __syncthreads();
    if (threadIdx.x == 0) *mode = any_nz ? 0 : 1;   // 1 => int64 storage
}

__device__ __forceinline__ int get_row(const int* ei, int e, int m) {
    return m ? ei[2 * e] : ei[e];
}
__device__ __forceinline__ int get_col(const int* ei, int e, int m) {
    return m ? ei[2 * NE + 2 * e] : ei[NE + e];
}

// ---------------- CSR build -------------------------------------------------
__global__ void count_kernel(const int* __restrict__ ei, int* __restrict__ deg,
                             const int* __restrict__ mode) {
    int e = blockIdx.x * 256 + threadIdx.x;
    int m = *mode;
    if (e < NE) atomicAdd(&deg[get_col(ei, e, m)], 1);
}

__global__ void scan1_kernel(const int* __restrict__ deg, int* __restrict__ offs,
                             int* __restrict__ bsums) {
    __shared__ int sd[256];
    int tid = threadIdx.x;
    int base = blockIdx.x * 1024 + tid * 4;
    int v[4]; int s = 0;
#pragma unroll
    for (int k = 0; k < 4; ++k) { v[k] = (base + k < NN) ? deg[base + k] : 0; s += v[k]; }
    sd[tid] = s;
    __syncthreads();
    for (int off = 1; off < 256; off <<= 1) {
        int t = (tid >= off) ? sd[tid - off] : 0;
        __syncthreads();
        sd[tid] += t;
        __syncthreads();
    }
    int excl = sd[tid] - s;
    if (tid == 255) bsums[blockIdx.x] = sd[255];
    int p = excl;
#pragma unroll
    for (int k = 0; k < 4; ++k) {
        if (base + k < NN) offs[base + k] = p;
        p += v[k];
    }
}

__global__ void scan2_kernel(int* __restrict__ bsums, int nb) {
    __shared__ int sd[128];
    int tid = threadIdx.x;
    int v = (tid < nb) ? bsums[tid] : 0;
    sd[tid] = v;
    __syncthreads();
    for (int off = 1; off < 128; off <<= 1) {
        int t = (tid >= off) ? sd[tid - off] : 0;
        __syncthreads();
        sd[tid] += t;
        __syncthreads();
    }
    if (tid < nb) bsums[tid] = sd[tid] - v;   // exclusive
}

__global__ void scan3_kernel(int* __restrict__ offs, const int* __restrict__ bsums,
                             int* __restrict__ cursor) {
    int i = blockIdx.x * 256 + threadIdx.x;
    if (i < NN) {
        int o = offs[i] + bsums[i >> 10];
        offs[i] = o;
        cursor[i] = o;
    }
    if (i == 0) offs[NN] = NE;
}

__global__ void fill_kernel(const int* __restrict__ ei, int* __restrict__ cursor,
                            int* __restrict__ srcs, const int* __restrict__ mode) {
    int e = blockIdx.x * 256 + threadIdx.x;
    int m = *mode;
    if (e < NE) {
        int c = get_col(ei, e, m);
        int p = atomicAdd(&cursor[c], 1);
        srcs[p] = get_row(ei, e, m);
    }
}

// ---------------- phase 1: per-node MLPs -> Q(f32), K(bf16), V(bf16) --------
__global__ __launch_bounds__(256) void phase1_kernel(
    const float* __restrict__ feat, const float* __restrict__ Win,
    const float* __restrict__ bin, const float* __restrict__ Wq,
    const float* __restrict__ bq, const float* __restrict__ Wk,
    const float* __restrict__ bk, const float* __restrict__ Wv,
    const float* __restrict__ bv, const float* __restrict__ hopwise,
    float* __restrict__ Qg, unsigned short* __restrict__ Kb,
    unsigned short* __restrict__ Vb, float* __restrict__ out)
{
    __shared__ float sWin[F_IN * CH];
    __shared__ float sWq[CH * CH];
    __shared__ float sWk[CH * CH];
    __shared__ float sWv[CH * NC];
    __shared__ float sbin[CH], sbq[CH], sbk[CH], sbv[NC];

    int tid = threadIdx.x;
    for (int i = tid; i < F_IN * CH; i += 256) sWin[i] = Win[i];
    for (int i = tid; i < CH * CH; i += 256) { sWq[i] = Wq[i]; sWk[i] = Wk[i]; }
    for (int i = tid; i < CH * NC; i += 256) sWv[i] = Wv[i];
    if (tid < CH) { sbin[tid] = bin[tid]; sbq[tid] = bq[tid]; sbk[tid] = bk[tid]; }
    if (tid < NC) sbv[tid] = bv[tid];
    __syncthreads();

    int wid  = tid >> 6;
    int lane = tid & 63;
    int half = lane >> 5;
    int c    = lane & 31;
    int node = (blockIdx.x * 4 + wid) * 2 + half;
    bool valid = node < NN;

    float x = 0.f;
    if (valid) {
        const float4* f4 = (const float4*)(feat + (size_t)node * F_IN);
#pragma unroll
        for (int t = 0; t < F_IN / 4; ++t) {
            float4 fv = f4[t];
            x += fv.x * sWin[(4 * t + 0) * CH + c];
            x += fv.y * sWin[(4 * t + 1) * CH + c];
            x += fv.z * sWin[(4 * t + 2) * CH + c];
            x += fv.w * sWin[(4 * t + 3) * CH + c];
        }
        x += sbin[c];
        x = fmaxf(x, 0.f);
    }

    float q = 0.f, k = 0.f, v = 0.f;
#pragma unroll
    for (int j = 0; j < CH; ++j) {
        float xj = __shfl(x, j, 32);
        q += xj * sWq[j * CH + c];
        k += xj * sWk[j * CH + c];
        if (c < NC) v += xj * sWv[j * NC + c];
    }
    q += sbq[c]; q = 1.f + ((q > 0.f) ? q : (expf(q) - 1.f));
    k += sbk[c]; k = 1.f + ((k > 0.f) ? k : (expf(k) - 1.f));

    if (valid) {
        Qg[(size_t)node * CH + c] = q;
        Kb[(size_t)node * CH + c] = (unsigned short)bf_round(k);
        if (c < NC) {
            float vv = v + sbv[c];
            Vb[(size_t)node * NC + c] = (unsigned short)bf_round(vv);
            out[(size_t)node * NC + c] = hopwise[0] * vv;
        }
    }
}

// ---------------- fallback K propagation (bf16) + sc ------------------------
__global__ __launch_bounds__(256) void kprop_kernel(
    const float* __restrict__ Qg, const unsigned short* __restrict__ Kin,
    unsigned short* __restrict__ Kout, const int* __restrict__ offs,
    const int* __restrict__ srcs, const float* __restrict__ hopw, int hop,
    float* __restrict__ sc)
{
    int tid = threadIdx.x;
    int wid = tid >> 6, lane = tid & 63;
    int half = lane >> 5, c = lane & 31;
    int node = blockIdx.x * 8 + wid * 2 + half;
    if (node >= NN) return;

    float k = 0.f;
    int s = offs[node], e = offs[node + 1];
    for (int i = s; i < e; ++i) k += bf_val(Kin[(size_t)srcs[i] * CH + c]);
    Kout[(size_t)node * CH + c] = (unsigned short)bf_round(k);

    float cp = Qg[(size_t)node * CH + c] * k;
#pragma unroll
    for (int m = 1; m < 32; m <<= 1) cp += __shfl_xor(cp, m, 32);
    if (c == 0) sc[node] = hopw[hop] / (cp + CSTF);
}

// ---------------- hop: gather M (fp8) / rank-1, fused K-agg + readout -------
// Chunk layout per node: CB*16 fp8 bytes; element f = lane*EPL + k,
// c = c0 + lane/L, j = EPL*(lane&(L-1)) + k, EPL=CB*16/64, L=16/EPL.
// FUSEK requires CB==32 (full c coverage, c0==0).
template<int CB, bool RANK1, bool WRITE, bool FUSEK>
__global__ __launch_bounds__(256) void hopc_kernel(
    const float* __restrict__ Qg, const unsigned short* __restrict__ Kb,
    const unsigned short* __restrict__ Vb, const unsigned char* __restrict__ Min,
    unsigned char* __restrict__ Mout, unsigned short* __restrict__ Kout,
    const int* __restrict__ offs, const int* __restrict__ srcs,
    const float* __restrict__ hopw, int hop, const float* __restrict__ scbuf,
    int c0, float* __restrict__ out)
{
    constexpr int EPL = CB * 16 / 64;     // 8, 4, 2, 1
    constexpr int L   = 16 / EPL;         // lanes per c-row
    int tid = threadIdx.x;
    int wid = tid >> 6, lane = tid & 63;
    int node = blockIdx.x * 4 + wid;
    if (node >= NN) return;

    int jb = EPL * (lane & (L - 1));
    int cl = lane / L;                    // 0..CB-1

    float acc[EPL];
#pragma unroll
    for (int k = 0; k < EPL; ++k) acc[k] = 0.f;
    float kagg = 0.f;

    int s = offs[node], e = offs[node + 1];
    for (int i = s; i < e; ++i) {
        int src = srcs[i];
        if (RANK1) {
            float kc = bf_val(Kb[(size_t)src * CH + c0 + cl]);
            if (FUSEK) kagg += kc;
            const unsigned short* vp = Vb + (size_t)src * NC + jb;
            if (EPL == 8) {
                uint4 u = *(const uint4*)vp;
                acc[0] += kc * bf_lo(u.x); acc[1] += kc * bf_hi(u.x);
                acc[2] += kc * bf_lo(u.y); acc[3] += kc * bf_hi(u.y);
                acc[4] += kc * bf_lo(u.z); acc[5] += kc * bf_hi(u.z);
                acc[6] += kc * bf_lo(u.w); acc[7] += kc * bf_hi(u.w);
            } else if (EPL == 4) {
                uint2 u = *(const uint2*)vp;
                acc[0] += kc * bf_lo(u.x); acc[1] += kc * bf_hi(u.x);
                acc[2] += kc * bf_lo(u.y); acc[3] += kc * bf_hi(u.y);
            } else if (EPL == 2) {
                unsigned int u = *(const unsigned int*)vp;
                acc[0] += kc * bf_lo(u); acc[1] += kc * bf_hi(u);
            } else {
                acc[0] += kc * bf_val(vp[0]);
            }
        } else {
            if (FUSEK) kagg += bf_val(Kb[(size_t)src * CH + cl]);
            const unsigned char* mi = Min + (size_t)src * (CB * 16) + lane * EPL;
            if (EPL == 8) {
                uint2 u = *(const uint2*)mi;
                auto f0 = __builtin_amdgcn_cvt_pk_f32_fp8(u.x, false);
                auto f1 = __builtin_amdgcn_cvt_pk_f32_fp8(u.x, true);
                auto f2 = __builtin_amdgcn_cvt_pk_f32_fp8(u.y, false);
                auto f3 = __builtin_amdgcn_cvt_pk_f32_fp8(u.y, true);
                acc[0] += f0[0]; acc[1] += f0[1]; acc[2] += f1[0]; acc[3] += f1[1];
                acc[4] += f2[0]; acc[5] += f2[1]; acc[6] += f3[0]; acc[7] += f3[1];
            } else if (EPL == 4) {
                unsigned int u = *(const unsigned int*)mi;
                auto f0 = __builtin_amdgcn_cvt_pk_f32_fp8(u, false);
                auto f1 = __builtin_amdgcn_cvt_pk_f32_fp8(u, true);
                acc[0] += f0[0]; acc[1] += f0[1]; acc[2] += f1[0]; acc[3] += f1[1];
            } else if (EPL == 2) {
                unsigned int u = *(const unsigned short*)mi;
                auto f0 = __builtin_amdgcn_cvt_pk_f32_fp8(u, false);
                acc[0] += f0[0]; acc[1] += f0[1];
            } else {
                unsigned int u = *mi;
                auto f0 = __builtin_amdgcn_cvt_pk_f32_fp8(u, false);
                acc[0] += f0[0];
            }
        }
    }

    float q = Qg[(size_t)node * CH + c0 + cl];

    float myscale;
    if (FUSEK) {
        if (WRITE && (lane & (L - 1)) == 0)
            Kout[(size_t)node * CH + cl] = (unsigned short)bf_round(kagg);
        float cp = q * kagg;                       // each c counted L times
#pragma unroll
        for (int m = 1; m < 64; m <<= 1) cp += __shfl_xor(cp, m);
        myscale = hopw[hop] / (cp * (1.f / L) + CSTF);
    } else {
        myscale = scbuf[node];
    }

    if (WRITE) {
        unsigned char* mo = Mout + (size_t)node * (CB * 16) + lane * EPL;
        if (EPL == 8) {
            int p0 = 0, p1 = 0;
            p0 = __builtin_amdgcn_cvt_pk_fp8_f32(cl448(acc[0]), cl448(acc[1]), p0, false);
            p0 = __builtin_amdgcn_cvt_pk_fp8_f32(cl448(acc[2]), cl448(acc[3]), p0, true);
            p1 = __builtin_amdgcn_cvt_pk_fp8_f32(cl448(acc[4]), cl448(acc[5]), p1, false);
            p1 = __builtin_amdgcn_cvt_pk_fp8_f32(cl448(acc[6]), cl448(acc[7]), p1, true);
            uint2 u; u.x = (unsigned int)p0; u.y = (unsigned int)p1;
            *(uint2*)mo = u;
        } else if (EPL == 4) {
            int p0 = 0;
            p0 = __builtin_amdgcn_cvt_pk_fp8_f32(cl448(acc[0]), cl448(acc[1]), p0, false);
            p0 = __builtin_amdgcn_cvt_pk_fp8_f32(cl448(acc[2]), cl448(acc[3]), p0, true);
            *(unsigned int*)mo = (unsigned int)p0;
        } else if (EPL == 2) {
            int p0 = __builtin_amdgcn_cvt_pk_fp8_f32(cl448(acc[0]), cl448(acc[1]), 0, false);
            *(unsigned short*)mo = (unsigned short)(p0 & 0xffff);
        } else {
            int p0 = __builtin_amdgcn_cvt_pk_fp8_f32(cl448(acc[0]), 0.f, 0, false);
            *mo = (unsigned char)(p0 & 0xff);
        }
    }

    // readout: H[j] = sum_c Q[c]*M[c,j]; out += sc*H
    float h[EPL];
#pragma unroll
    for (int k = 0; k < EPL; ++k) h[k] = q * acc[k];
#pragma unroll
    for (int st = L; st < 64; st <<= 1) {
#pragma unroll
        for (int k = 0; k < EPL; ++k) h[k] += __shfl_xor(h[k], st);
    }
    if (lane < L) {
#pragma unroll
        for (int k = 0; k < EPL; ++k)
            out[(size_t)node * NC + jb + k] += myscale * h[k];
    }
}

template<int CB>
static void run_chunks(const float* Qg, const unsigned short* K0b,
                       const unsigned short* Vb, unsigned char* MA,
                       unsigned char* MB, const int* offs, const int* srcs,
                       const float* sc1, const float* sc2, const float* sc3,
                       const float* hopw, float* out, hipStream_t stream)
{
    for (int c0 = 0; c0 < CH; c0 += CB) {
        hopc_kernel<CB, true,  true,  false><<<25000, 256, 0, stream>>>(Qg, K0b, Vb, nullptr, MA, nullptr, offs, srcs, hopw, 1, sc1, c0, out);
        hopc_kernel<CB, false, true,  false><<<25000, 256, 0, stream>>>(Qg, K0b, Vb, MA, MB, nullptr, offs, srcs, hopw, 2, sc2, c0, out);
        hopc_kernel<CB, false, false, false><<<25000, 256, 0, stream>>>(Qg, K0b, Vb, MB, nullptr, nullptr, offs, srcs, hopw, 3, sc3, c0, out);
    }
}

// ---------------- launch ----------------------------------------------------
extern "C" void kernel_launch(void* const* d_in, const int* in_sizes, int n_in,
                              void* d_out, int out_size, void* d_ws, size_t ws_size,
                              hipStream_t stream) {
    const float* feat = (const float*)d_in[0];
    const int*   ei   = (const int*)d_in[1];
    const float* Win  = (const float*)d_in[2];
    const float* bin  = (const float*)d_in[3];
    const float* Wq   = (const float*)d_in[4];
    const float* bq   = (const float*)d_in[5];
    const float* Wk   = (const float*)d_in[6];
    const float* bk   = (const float*)d_in[7];
    const float* Wv   = (const float*)d_in[8];
    const float* bv   = (const float*)d_in[9];
    const float* hopw = (const float*)d_in[10];
    float* out = (float*)d_out;

    char* ws = (char*)d_ws;
    size_t off = 0;
    auto alloc = [&](size_t bytes) -> void* {
        void* p = ws + off;
        off += (bytes + 255) & ~(size_t)255;
        return p;
    };
    float*          Qg  = (float*)alloc((size_t)NN * CH * 4);
    unsigned short* K0b = (unsigned short*)alloc((size_t)NN * CH * 2);
    unsigned short* K1b = (unsigned short*)alloc((size_t)NN * CH * 2);
    unsigned short* K2b = (unsigned short*)alloc((size_t)NN * CH * 2);
    unsigned short* K3b = (unsigned short*)alloc((size_t)NN * CH * 2);
    unsigned short* Vb  = (unsigned short*)alloc((size_t)NN * NC * 2);
    float* sc1 = (float*)alloc((size_t)NN * 4);
    float* sc2 = (float*)alloc((size_t)NN * 4);
    float* sc3 = (float*)alloc((size_t)NN * 4);
    int*   deg = (int*)alloc((size_t)NN * 4);
    int*   offs   = (int*)alloc((size_t)(NN + 1) * 4);
    int*   cursor = (int*)alloc((size_t)NN * 4);
    int*   bsums  = (int*)alloc(512);
    int*   mode   = (int*)alloc(4);
    int*   srcs   = (int*)alloc((size_t)NE * 4);
    size_t fixed = off;

    // fp8 M ping-pong: CB*16 bytes per node per buffer
    auto mbytes = [](int cb) { return (size_t)NN * cb * 16; };
    int CB = 4;
    if      (ws_size >= fixed + 2 * mbytes(32) + 512) CB = 32;
    else if (ws_size >= fixed + 2 * mbytes(16) + 512) CB = 16;
    else if (ws_size >= fixed + 2 * mbytes(8)  + 512) CB = 8;
    unsigned char* MA = (unsigned char*)alloc(mbytes(CB));
    unsigned char* MB = (unsigned char*)alloc(mbytes(CB));

    // CSR build
    zero_kernel<<<(NN + 255) / 256, 256, 0, stream>>>(deg, NN);
    detect_kernel<<<1, 256, 0, stream>>>(ei, mode);
    count_kernel<<<(NE + 255) / 256, 256, 0, stream>>>(ei, deg, mode);
    int nb = (NN + 1023) / 1024;
    scan1_kernel<<<nb, 256, 0, stream>>>(deg, offs, bsums);
    scan2_kernel<<<1, 128, 0, stream>>>(bsums, nb);
    scan3_kernel<<<(NN + 255) / 256, 256, 0, stream>>>(offs, bsums, cursor);
    fill_kernel<<<(NE + 255) / 256, 256, 0, stream>>>(ei, cursor, srcs, mode);

    // node-wise MLPs
    phase1_kernel<<<12500, 256, 0, stream>>>(feat, Win, bin, Wq, bq, Wk, bk, Wv, bv,
                                             hopw, Qg, K0b, Vb, out);

    if (CB == 32) {
        // fused path: K-agg + C + scale inside the hop kernels
        hopc_kernel<32, true,  true,  true><<<25000, 256, 0, stream>>>(Qg, K0b, Vb, nullptr, MA, K1b, offs, srcs, hopw, 1, nullptr, 0, out);
        hopc_kernel<32, false, true,  true><<<25000, 256, 0, stream>>>(Qg, K1b, Vb, MA, MB, K2b, offs, srcs, hopw, 2, nullptr, 0, out);
        hopc_kernel<32, false, false, true><<<25000, 256, 0, stream>>>(Qg, K2b, Vb, MB, nullptr, nullptr, offs, srcs, hopw, 3, nullptr, 0, out);
    } else {
        kprop_kernel<<<12500, 256, 0, stream>>>(Qg, K0b, K1b, offs, srcs, hopw, 1, sc1);
        kprop_kernel<<<12500, 256, 0, stream>>>(Qg, K1b, K2b, offs, srcs, hopw, 2, sc2);
        kprop_kernel<<<12500, 256, 0, stream>>>(Qg, K2b, K3b, offs, srcs, hopw, 3, sc3);
        if      (CB == 16) run_chunks<16>(Qg, K0b, Vb, MA, MB, offs, srcs, sc1, sc2, sc3, hopw, out, stream);
        else if (CB == 8)  run_chunks<8> (Qg, K0b, Vb, MA, MB, offs, srcs, sc1, sc2, sc3, hopw, out, stream);
        else               run_chunks<4> (Qg, K0b, Vb, MA, MB, offs, srcs, sc1, sc2, sc3, hopw, out, stream);
    }
}

// Round 6
// 543.028 us; speedup vs baseline: 2.1238x; 1.1587x over previous
//
#include <hip/hip_runtime.h>
#include <math.h>

#define NN 100000
#define NE 800000
#define F_IN 128
#define CH 32
#define NC 16
#define CSTF 1e-5f

typedef float v4f __attribute__((ext_vector_type(4)));
typedef short v8s __attribute__((ext_vector_type(8)));

// ---------------- bf16 helpers ----------------------------------------------
__device__ __forceinline__ float bf_lo(unsigned int u) {
    unsigned int t = u << 16;
    return __builtin_bit_cast(float, t);
}
__device__ __forceinline__ float bf_hi(unsigned int u) {
    unsigned int t = u & 0xffff0000u;
    return __builtin_bit_cast(float, t);
}
__device__ __forceinline__ float bf_val(unsigned short v) {
    unsigned int t = ((unsigned int)v) << 16;
    return __builtin_bit_cast(float, t);
}
__device__ __forceinline__ unsigned int bf_round(float a) {
    unsigned int ua = __builtin_bit_cast(unsigned int, a);
    return (ua + 0x7fffu + ((ua >> 16) & 1u)) >> 16;     // RNE, a finite
}
__device__ __forceinline__ short bfq(float a) {          // fast round to nearest
    unsigned int ua = __builtin_bit_cast(unsigned int, a);
    return (short)((ua + 0x8000u) >> 16);
}

// fp8 e4m3 clamp: avoid NaN on overflow (max normal = 448)
__device__ __forceinline__ float cl448(float a) {
    return fminf(fmaxf(a, -448.f), 448.f);
}

__device__ __forceinline__ float elu1(float x) {
    return 1.f + ((x > 0.f) ? x : (expf(x) - 1.f));
}

// ---------------- utility ---------------------------------------------------
__global__ void zero_kernel(int* __restrict__ p, int n) {
    int i = blockIdx.x * 256 + threadIdx.x;
    if (i < n) p[i] = 0;
}

// ---------------- edge dtype detection (int32 vs int64 storage) -------------
__global__ void detect_kernel(const int* __restrict__ ei, int* __restrict__ mode) {
    __shared__ int any_nz;
    if (threadIdx.x == 0) any_nz = 0;
    __syncthreads();
    int nz = 0;
    for (int i = threadIdx.x; i < 4096; i += 256) nz |= (ei[2 * i + 1] != 0);
    if (nz) atomicOr(&any_nz, 1);
    __syncthreads();
    if (threadIdx.x == 0) *mode = any_nz ? 0 : 1;   // 1 => int64 storage
}

__device__ __forceinline__ int get_row(const int* ei, int e, int m) {
    return m ? ei[2 * e] : ei[e];
}
__device__ __forceinline__ int get_col(const int* ei, int e, int m) {
    return m ? ei[2 * NE + 2 * e] : ei[NE + e];
}

// ---------------- CSR build -------------------------------------------------
__global__ void count_kernel(const int* __restrict__ ei, int* __restrict__ deg,
                             const int* __restrict__ mode) {
    int e = blockIdx.x * 256 + threadIdx.x;
    int m = *mode;
    if (e < NE) atomicAdd(&deg[get_col(ei, e, m)], 1);
}

__global__ void scan1_kernel(const int* __restrict__ deg, int* __restrict__ offs,
                             int* __restrict__ bsums) {
    __shared__ int sd[256];
    int tid = threadIdx.x;
    int base = blockIdx.x * 1024 + tid * 4;
    int v[4]; int s = 0;
#pragma unroll
    for (int k = 0; k < 4; ++k) { v[k] = (base + k < NN) ? deg[base + k] : 0; s += v[k]; }
    sd[tid] = s;
    __syncthreads();
    for (int off = 1; off < 256; off <<= 1) {
        int t = (tid >= off) ? sd[tid - off] : 0;
        __syncthreads();
        sd[tid] += t;
        __syncthreads();
    }
    int excl = sd[tid] - s;
    if (tid == 255) bsums[blockIdx.x] = sd[255];
    int p = excl;
#pragma unroll
    for (int k = 0; k < 4; ++k) {
        if (base + k < NN) offs[base + k] = p;
        p += v[k];
    }
}

__global__ void scan2_kernel(int* __restrict__ bsums, int nb) {
    __shared__ int sd[128];
    int tid = threadIdx.x;
    int v = (tid < nb) ? bsums[tid] : 0;
    sd[tid] = v;
    __syncthreads();
    for (int off = 1; off < 128; off <<= 1) {
        int t = (tid >= off) ? sd[tid - off] : 0;
        __syncthreads();
        sd[tid] += t;
        __syncthreads();
    }
    if (tid < nb) bsums[tid] = sd[tid] - v;   // exclusive
}

__global__ void scan3_kernel(int* __restrict__ offs, const int* __restrict__ bsums,
                             int* __restrict__ cursor) {
    int i = blockIdx.x * 256 + threadIdx.x;
    if (i < NN) {
        int o = offs[i] + bsums[i >> 10];
        offs[i] = o;
        cursor[i] = o;
    }
    if (i == 0) offs[NN] = NE;
}

__global__ void fill_kernel(const int* __restrict__ ei, int* __restrict__ cursor,
                            int* __restrict__ srcs, const int* __restrict__ mode) {
    int e = blockIdx.x * 256 + threadIdx.x;
    int m = *mode;
    if (e < NE) {
        int c = get_col(ei, e, m);
        int p = atomicAdd(&cursor[c], 1);
        srcs[p] = get_row(ei, e, m);
    }
}

// ---------------- phase 1 (MFMA): per-node MLPs -> Q(f32), K(bf16), V(bf16) -
// One wave = 16 nodes. GEMM1: x = relu(feat@Win+b), 2 N-tiles x 4 K-steps.
// A-frags from global (row-contiguous 128B chunks); B-frags in registers.
// C->A layout transform via per-wave LDS tile (stride 36 words: 2 lanes/bank).
__global__ __launch_bounds__(256) void phase1_kernel(
    const float* __restrict__ feat, const float* __restrict__ Win,
    const float* __restrict__ bin, const float* __restrict__ Wq,
    const float* __restrict__ bq, const float* __restrict__ Wk,
    const float* __restrict__ bk, const float* __restrict__ Wv,
    const float* __restrict__ bv, const float* __restrict__ hopwise,
    float* __restrict__ Qg, unsigned short* __restrict__ Kb,
    unsigned short* __restrict__ Vb, float* __restrict__ out)
{
    __shared__ float xs_all[4][16 * 36];       // 9216 B

    int tid  = threadIdx.x;
    int wid  = tid >> 6;
    int lane = tid & 63;
    int q    = lane >> 4;        // quad 0..3
    int col  = lane & 15;
    int node0 = (blockIdx.x * 4 + wid) * 16;

    // ---- weight B-frags (registers). B[k][n]: n=col, k=q*8+j.
    v8s wb[4][2];                // Win: [kk][ntile]
#pragma unroll
    for (int kk = 0; kk < 4; ++kk)
#pragma unroll
        for (int t = 0; t < 2; ++t)
#pragma unroll
            for (int j = 0; j < 8; ++j)
                wb[kk][t][j] = (short)bf_round(Win[(kk * 32 + q * 8 + j) * CH + t * 16 + col]);

    v8s wq[2], wk[2], wv;
#pragma unroll
    for (int t = 0; t < 2; ++t)
#pragma unroll
        for (int j = 0; j < 8; ++j) {
            wq[t][j] = (short)bf_round(Wq[(q * 8 + j) * CH + t * 16 + col]);
            wk[t][j] = (short)bf_round(Wk[(q * 8 + j) * CH + t * 16 + col]);
        }
#pragma unroll
    for (int j = 0; j < 8; ++j)
        wv[j] = (short)bf_round(Wv[(q * 8 + j) * NC + col]);

    float bin0 = bin[col], bin1 = bin[col + 16];
    float bq0 = bq[col], bq1 = bq[col + 16];
    float bk0 = bk[col], bk1 = bk[col + 16];
    float bv0 = bv[col];
    float hw0 = hopwise[0];

    // ---- GEMM1: A[m][k], m=col (node), k=q*8+j
    int nodeA = node0 + col;
    int nclamp = nodeA < NN ? nodeA : NN - 1;
    const float* fr = feat + (size_t)nclamp * F_IN + q * 8;

    v4f acc0 = {0.f, 0.f, 0.f, 0.f}, acc1 = {0.f, 0.f, 0.f, 0.f};
#pragma unroll
    for (int kk = 0; kk < 4; ++kk) {
        float4 a = *(const float4*)(fr + kk * 32);
        float4 b = *(const float4*)(fr + kk * 32 + 4);
        v8s af;
        af[0] = bfq(a.x); af[1] = bfq(a.y); af[2] = bfq(a.z); af[3] = bfq(a.w);
        af[4] = bfq(b.x); af[5] = bfq(b.y); af[6] = bfq(b.z); af[7] = bfq(b.w);
        acc0 = __builtin_amdgcn_mfma_f32_16x16x32_bf16(af, wb[kk][0], acc0, 0, 0, 0);
        acc1 = __builtin_amdgcn_mfma_f32_16x16x32_bf16(af, wb[kk][1], acc1, 0, 0, 0);
    }

    // ---- bias + relu; C-layout (row=4q+r, col) -> LDS x[m][ch], stride 36
    float* xs = xs_all[wid];
#pragma unroll
    for (int r = 0; r < 4; ++r) {
        xs[(q * 4 + r) * 36 + col]      = fmaxf(acc0[r] + bin0, 0.f);
        xs[(q * 4 + r) * 36 + col + 16] = fmaxf(acc1[r] + bin1, 0.f);
    }

    // ---- read A-frag for GEMM2: m=col, k=q*8+j (8 consecutive channels)
    float4 xa = *(const float4*)&xs[col * 36 + q * 8];
    float4 xb = *(const float4*)&xs[col * 36 + q * 8 + 4];
    v8s xf;
    xf[0] = bfq(xa.x); xf[1] = bfq(xa.y); xf[2] = bfq(xa.z); xf[3] = bfq(xa.w);
    xf[4] = bfq(xb.x); xf[5] = bfq(xb.y); xf[6] = bfq(xb.z); xf[7] = bfq(xb.w);

    v4f aq0 = {0.f,0.f,0.f,0.f}, aq1 = {0.f,0.f,0.f,0.f};
    v4f ak0 = {0.f,0.f,0.f,0.f}, ak1 = {0.f,0.f,0.f,0.f};
    v4f av  = {0.f,0.f,0.f,0.f};
    aq0 = __builtin_amdgcn_mfma_f32_16x16x32_bf16(xf, wq[0], aq0, 0, 0, 0);
    aq1 = __builtin_amdgcn_mfma_f32_16x16x32_bf16(xf, wq[1], aq1, 0, 0, 0);
    ak0 = __builtin_amdgcn_mfma_f32_16x16x32_bf16(xf, wk[0], ak0, 0, 0, 0);
    ak1 = __builtin_amdgcn_mfma_f32_16x16x32_bf16(xf, wk[1], ak1, 0, 0, 0);
    av  = __builtin_amdgcn_mfma_f32_16x16x32_bf16(xf, wv,    av,  0, 0, 0);

    // ---- epilogue: C-layout row = node0 + 4q + r, col
#pragma unroll
    for (int r = 0; r < 4; ++r) {
        int nd = node0 + 4 * q + r;
        if (nd < NN) {
            float q0 = elu1(aq0[r] + bq0);
            float q1 = elu1(aq1[r] + bq1);
            float k0 = elu1(ak0[r] + bk0);
            float k1 = elu1(ak1[r] + bk1);
            float vv = av[r] + bv0;
            Qg[(size_t)nd * CH + col]      = q0;
            Qg[(size_t)nd * CH + col + 16] = q1;
            Kb[(size_t)nd * CH + col]      = (unsigned short)bf_round(k0);
            Kb[(size_t)nd * CH + col + 16] = (unsigned short)bf_round(k1);
            Vb[(size_t)nd * NC + col]      = (unsigned short)bf_round(vv);
            out[(size_t)nd * NC + col]     = hw0 * vv;
        }
    }
}

// ---------------- fallback K propagation (bf16) + sc ------------------------
__global__ __launch_bounds__(256) void kprop_kernel(
    const float* __restrict__ Qg, const unsigned short* __restrict__ Kin,
    unsigned short* __restrict__ Kout, const int* __restrict__ offs,
    const int* __restrict__ srcs, const float* __restrict__ hopw, int hop,
    float* __restrict__ sc)
{
    int tid = threadIdx.x;
    int wid = tid >> 6, lane = tid & 63;
    int half = lane >> 5, c = lane & 31;
    int node = blockIdx.x * 8 + wid * 2 + half;
    if (node >= NN) return;

    float k = 0.f;
    int s = offs[node], e = offs[node + 1];
    for (int i = s; i < e; ++i) k += bf_val(Kin[(size_t)srcs[i] * CH + c]);
    Kout[(size_t)node * CH + c] = (unsigned short)bf_round(k);

    float cp = Qg[(size_t)node * CH + c] * k;
#pragma unroll
    for (int m = 1; m < 32; m <<= 1) cp += __shfl_xor(cp, m, 32);
    if (c == 0) sc[node] = hopw[hop] / (cp + CSTF);
}

// ---------------- hop: gather M (fp8) / rank-1, fused K-agg + readout -------
template<int CB, bool RANK1, bool WRITE, bool FUSEK>
__global__ __launch_bounds__(256) void hopc_kernel(
    const float* __restrict__ Qg, const unsigned short* __restrict__ Kb,
    const unsigned short* __restrict__ Vb, const unsigned char* __restrict__ Min,
    unsigned char* __restrict__ Mout, unsigned short* __restrict__ Kout,
    const int* __restrict__ offs, const int* __restrict__ srcs,
    const float* __restrict__ hopw, int hop, const float* __restrict__ scbuf,
    int c0, float* __restrict__ out)
{
    constexpr int EPL = CB * 16 / 64;     // 8, 4, 2, 1
    constexpr int L   = 16 / EPL;         // lanes per c-row
    int tid = threadIdx.x;
    int wid = tid >> 6, lane = tid & 63;
    int node = blockIdx.x * 4 + wid;
    if (node >= NN) return;

    int jb = EPL * (lane & (L - 1));
    int cl = lane / L;                    // 0..CB-1

    float acc[EPL];
#pragma unroll
    for (int k = 0; k < EPL; ++k) acc[k] = 0.f;
    float kagg = 0.f;

    int s = offs[node], e = offs[node + 1];
    for (int i = s; i < e; ++i) {
        int src = srcs[i];
        if (RANK1) {
            float kc = bf_val(Kb[(size_t)src * CH + c0 + cl]);
            if (FUSEK) kagg += kc;
            const unsigned short* vp = Vb + (size_t)src * NC + jb;
            if (EPL == 8) {
                uint4 u = *(const uint4*)vp;
                acc[0] += kc * bf_lo(u.x); acc[1] += kc * bf_hi(u.x);
                acc[2] += kc * bf_lo(u.y); acc[3] += kc * bf_hi(u.y);
                acc[4] += kc * bf_lo(u.z); acc[5] += kc * bf_hi(u.z);
                acc[6] += kc * bf_lo(u.w); acc[7] += kc * bf_hi(u.w);
            } else if (EPL == 4) {
                uint2 u = *(const uint2*)vp;
                acc[0] += kc * bf_lo(u.x); acc[1] += kc * bf_hi(u.x);
                acc[2] += kc * bf_lo(u.y); acc[3] += kc * bf_hi(u.y);
            } else if (EPL == 2) {
                unsigned int u = *(const unsigned int*)vp;
                acc[0] += kc * bf_lo(u); acc[1] += kc * bf_hi(u);
            } else {
                acc[0] += kc * bf_val(vp[0]);
            }
        } else {
            if (FUSEK) kagg += bf_val(Kb[(size_t)src * CH + cl]);
            const unsigned char* mi = Min + (size_t)src * (CB * 16) + lane * EPL;
            if (EPL == 8) {
                uint2 u = *(const uint2*)mi;
                auto f0 = __builtin_amdgcn_cvt_pk_f32_fp8(u.x, false);
                auto f1 = __builtin_amdgcn_cvt_pk_f32_fp8(u.x, true);
                auto f2 = __builtin_amdgcn_cvt_pk_f32_fp8(u.y, false);
                auto f3 = __builtin_amdgcn_cvt_pk_f32_fp8(u.y, true);
                acc[0] += f0[0]; acc[1] += f0[1]; acc[2] += f1[0]; acc[3] += f1[1];
                acc[4] += f2[0]; acc[5] += f2[1]; acc[6] += f3[0]; acc[7] += f3[1];
            } else if (EPL == 4) {
                unsigned int u = *(const unsigned int*)mi;
                auto f0 = __builtin_amdgcn_cvt_pk_f32_fp8(u, false);
                auto f1 = __builtin_amdgcn_cvt_pk_f32_fp8(u, true);
                acc[0] += f0[0]; acc[1] += f0[1]; acc[2] += f1[0]; acc[3] += f1[1];
            } else if (EPL == 2) {
                unsigned int u = *(const unsigned short*)mi;
                auto f0 = __builtin_amdgcn_cvt_pk_f32_fp8(u, false);
                acc[0] += f0[0]; acc[1] += f0[1];
            } else {
                unsigned int u = *mi;
                auto f0 = __builtin_amdgcn_cvt_pk_f32_fp8(u, false);
                acc[0] += f0[0];
            }
        }
    }

    float q = Qg[(size_t)node * CH + c0 + cl];

    float myscale;
    if (FUSEK) {
        if (WRITE && (lane & (L - 1)) == 0)
            Kout[(size_t)node * CH + cl] = (unsigned short)bf_round(kagg);
        float cp = q * kagg;                       // each c counted L times
#pragma unroll
        for (int m = 1; m < 64; m <<= 1) cp += __shfl_xor(cp, m);
        myscale = hopw[hop] / (cp * (1.f / L) + CSTF);
    } else {
        myscale = scbuf[node];
    }

    if (WRITE) {
        unsigned char* mo = Mout + (size_t)node * (CB * 16) + lane * EPL;
        if (EPL == 8) {
            int p0 = 0, p1 = 0;
            p0 = __builtin_amdgcn_cvt_pk_fp8_f32(cl448(acc[0]), cl448(acc[1]), p0, false);
            p0 = __builtin_amdgcn_cvt_pk_fp8_f32(cl448(acc[2]), cl448(acc[3]), p0, true);
            p1 = __builtin_amdgcn_cvt_pk_fp8_f32(cl448(acc[4]), cl448(acc[5]), p1, false);
            p1 = __builtin_amdgcn_cvt_pk_fp8_f32(cl448(acc[6]), cl448(acc[7]), p1, true);
            uint2 u; u.x = (unsigned int)p0; u.y = (unsigned int)p1;
            *(uint2*)mo = u;
        } else if (EPL == 4) {
            int p0 = 0;
            p0 = __builtin_amdgcn_cvt_pk_fp8_f32(cl448(acc[0]), cl448(acc[1]), p0, false);
            p0 = __builtin_amdgcn_cvt_pk_fp8_f32(cl448(acc[2]), cl448(acc[3]), p0, true);
            *(unsigned int*)mo = (unsigned int)p0;
        } else if (EPL == 2) {
            int p0 = __builtin_amdgcn_cvt_pk_fp8_f32(cl448(acc[0]), cl448(acc[1]), 0, false);
            *(unsigned short*)mo = (unsigned short)(p0 & 0xffff);
        } else {
            int p0 = __builtin_amdgcn_cvt_pk_fp8_f32(cl448(acc[0]), 0.f, 0, false);
            *mo = (unsigned char)(p0 & 0xff);
        }
    }

    // readout: H[j] = sum_c Q[c]*M[c,j]; out += sc*H
    float h[EPL];
#pragma unroll
    for (int k = 0; k < EPL; ++k) h[k] = q * acc[k];
#pragma unroll
    for (int st = L; st < 64; st <<= 1) {
#pragma unroll
        for (int k = 0; k < EPL; ++k) h[k] += __shfl_xor(h[k], st);
    }
    if (lane < L) {
#pragma unroll
        for (int k = 0; k < EPL; ++k)
            out[(size_t)node * NC + jb + k] += myscale * h[k];
    }
}

template<int CB>
static void run_chunks(const float* Qg, const unsigned short* K0b,
                       const unsigned short* Vb, unsigned char* MA,
                       unsigned char* MB, const int* offs, const int* srcs,
                       const float* sc1, const float* sc2, const float* sc3,
                       const float* hopw, float* out, hipStream_t stream)
{
    for (int c0 = 0; c0 < CH; c0 += CB) {
        hopc_kernel<CB, true,  true,  false><<<25000, 256, 0, stream>>>(Qg, K0b, Vb, nullptr, MA, nullptr, offs, srcs, hopw, 1, sc1, c0, out);
        hopc_kernel<CB, false, true,  false><<<25000, 256, 0, stream>>>(Qg, K0b, Vb, MA, MB, nullptr, offs, srcs, hopw, 2, sc2, c0, out);
        hopc_kernel<CB, false, false, false><<<25000, 256, 0, stream>>>(Qg, K0b, Vb, MB, nullptr, nullptr, offs, srcs, hopw, 3, sc3, c0, out);
    }
}

// ---------------- launch ----------------------------------------------------
extern "C" void kernel_launch(void* const* d_in, const int* in_sizes, int n_in,
                              void* d_out, int out_size, void* d_ws, size_t ws_size,
                              hipStream_t stream) {
    const float* feat = (const float*)d_in[0];
    const int*   ei   = (const int*)d_in[1];
    const float* Win  = (const float*)d_in[2];
    const float* bin  = (const float*)d_in[3];
    const float* Wq   = (const float*)d_in[4];
    const float* bq   = (const float*)d_in[5];
    const float* Wk   = (const float*)d_in[6];
    const float* bk   = (const float*)d_in[7];
    const float* Wv   = (const float*)d_in[8];
    const float* bv   = (const float*)d_in[9];
    const float* hopw = (const float*)d_in[10];
    float* out = (float*)d_out;

    char* ws = (char*)d_ws;
    size_t off = 0;
    auto alloc = [&](size_t bytes) -> void* {
        void* p = ws + off;
        off += (bytes + 255) & ~(size_t)255;
        return p;
    };
    float*          Qg  = (float*)alloc((size_t)NN * CH * 4);
    unsigned short* K0b = (unsigned short*)alloc((size_t)NN * CH * 2);
    unsigned short* K1b = (unsigned short*)alloc((size_t)NN * CH * 2);
    unsigned short* K2b = (unsigned short*)alloc((size_t)NN * CH * 2);
    unsigned short* K3b = (unsigned short*)alloc((size_t)NN * CH * 2);
    unsigned short* Vb  = (unsigned short*)alloc((size_t)NN * NC * 2);
    float* sc1 = (float*)alloc((size_t)NN * 4);
    float* sc2 = (float*)alloc((size_t)NN * 4);
    float* sc3 = (float*)alloc((size_t)NN * 4);
    int*   deg = (int*)alloc((size_t)NN * 4);
    int*   offs   = (int*)alloc((size_t)(NN + 1) * 4);
    int*   cursor = (int*)alloc((size_t)NN * 4);
    int*   bsums  = (int*)alloc(512);
    int*   mode   = (int*)alloc(4);
    int*   srcs   = (int*)alloc((size_t)NE * 4);
    size_t fixed = off;

    // fp8 M ping-pong: CB*16 bytes per node per buffer
    auto mbytes = [](int cb) { return (size_t)NN * cb * 16; };
    int CB = 4;
    if      (ws_size >= fixed + 2 * mbytes(32) + 512) CB = 32;
    else if (ws_size >= fixed + 2 * mbytes(16) + 512) CB = 16;
    else if (ws_size >= fixed + 2 * mbytes(8)  + 512) CB = 8;
    unsigned char* MA = (unsigned char*)alloc(mbytes(CB));
    unsigned char* MB = (unsigned char*)alloc(mbytes(CB));

    // CSR build
    zero_kernel<<<(NN + 255) / 256, 256, 0, stream>>>(deg, NN);
    detect_kernel<<<1, 256, 0, stream>>>(ei, mode);
    count_kernel<<<(NE + 255) / 256, 256, 0, stream>>>(ei, deg, mode);
    int nb = (NN + 1023) / 1024;
    scan1_kernel<<<nb, 256, 0, stream>>>(deg, offs, bsums);
    scan2_kernel<<<1, 128, 0, stream>>>(bsums, nb);
    scan3_kernel<<<(NN + 255) / 256, 256, 0, stream>>>(offs, bsums, cursor);
    fill_kernel<<<(NE + 255) / 256, 256, 0, stream>>>(ei, cursor, srcs, mode);

    // node-wise MLPs (MFMA)
    phase1_kernel<<<1563, 256, 0, stream>>>(feat, Win, bin, Wq, bq, Wk, bk, Wv, bv,
                                            hopw, Qg, K0b, Vb, out);

    if (CB == 32) {
        // fused path: K-agg + C + scale inside the hop kernels
        hopc_kernel<32, true,  true,  true><<<25000, 256, 0, stream>>>(Qg, K0b, Vb, nullptr, MA, K1b, offs, srcs, hopw, 1, nullptr, 0, out);
        hopc_kernel<32, false, true,  true><<<25000, 256, 0, stream>>>(Qg, K1b, Vb, MA, MB, K2b, offs, srcs, hopw, 2, nullptr, 0, out);
        hopc_kernel<32, false, false, true><<<25000, 256, 0, stream>>>(Qg, K2b, Vb, MB, nullptr, nullptr, offs, srcs, hopw, 3, nullptr, 0, out);
    } else {
        kprop_kernel<<<12500, 256, 0, stream>>>(Qg, K0b, K1b, offs, srcs, hopw, 1, sc1);
        kprop_kernel<<<12500, 256, 0, stream>>>(Qg, K1b, K2b, offs, srcs, hopw, 2, sc2);
        kprop_kernel<<<12500, 256, 0, stream>>>(Qg, K2b, K3b, offs, srcs, hopw, 3, sc3);
        if      (CB == 16) run_chunks<16>(Qg, K0b, Vb, MA, MB, offs, srcs, sc1, sc2, sc3, hopw, out, stream);
        else if (CB == 8)  run_chunks<8> (Qg, K0b, Vb, MA, MB, offs, srcs, sc1, sc2, sc3, hopw, out, stream);
        else               run_chunks<4> (Qg, K0b, Vb, MA, MB, offs, srcs, sc1, sc2, sc3, hopw, out, stream);
    }
}

// Round 7
// 537.796 us; speedup vs baseline: 2.1445x; 1.0097x over previous
//
#include <hip/hip_runtime.h>
#include <math.h>

#define NN 100000
#define NE 800000
#define F_IN 128
#define CH 32
#define NC 16
#define CSTF 1e-5f

typedef float v4f __attribute__((ext_vector_type(4)));
typedef short v8s __attribute__((ext_vector_type(8)));

// ---------------- bf16 helpers ----------------------------------------------
__device__ __forceinline__ float bf_lo(unsigned int u) {
    unsigned int t = u << 16;
    return __builtin_bit_cast(float, t);
}
__device__ __forceinline__ float bf_hi(unsigned int u) {
    unsigned int t = u & 0xffff0000u;
    return __builtin_bit_cast(float, t);
}
__device__ __forceinline__ float bf_val(unsigned short v) {
    unsigned int t = ((unsigned int)v) << 16;
    return __builtin_bit_cast(float, t);
}
__device__ __forceinline__ unsigned int bf_round(float a) {
    unsigned int ua = __builtin_bit_cast(unsigned int, a);
    return (ua + 0x7fffu + ((ua >> 16) & 1u)) >> 16;     // RNE, a finite
}
__device__ __forceinline__ short bfq(float a) {          // fast round to nearest
    unsigned int ua = __builtin_bit_cast(unsigned int, a);
    return (short)((ua + 0x8000u) >> 16);
}

// fp8 e4m3 clamp: avoid NaN on overflow (max normal = 448)
__device__ __forceinline__ float cl448(float a) {
    return fminf(fmaxf(a, -448.f), 448.f);
}

__device__ __forceinline__ float elu1(float x) {
    return 1.f + ((x > 0.f) ? x : (expf(x) - 1.f));
}

// accumulate 16 bf16 V values scaled by kc
__device__ __forceinline__ void acc_kv(float* acc, float kc, uint4 a, uint4 b) {
    acc[0]  += kc * bf_lo(a.x); acc[1]  += kc * bf_hi(a.x);
    acc[2]  += kc * bf_lo(a.y); acc[3]  += kc * bf_hi(a.y);
    acc[4]  += kc * bf_lo(a.z); acc[5]  += kc * bf_hi(a.z);
    acc[6]  += kc * bf_lo(a.w); acc[7]  += kc * bf_hi(a.w);
    acc[8]  += kc * bf_lo(b.x); acc[9]  += kc * bf_hi(b.x);
    acc[10] += kc * bf_lo(b.y); acc[11] += kc * bf_hi(b.y);
    acc[12] += kc * bf_lo(b.z); acc[13] += kc * bf_hi(b.z);
    acc[14] += kc * bf_lo(b.w); acc[15] += kc * bf_hi(b.w);
}

// accumulate 16 fp8 values from a uint4
__device__ __forceinline__ void acc_m16(float* acc, uint4 u) {
    v4f t;
    {
        auto f0 = __builtin_amdgcn_cvt_pk_f32_fp8(u.x, false);
        auto f1 = __builtin_amdgcn_cvt_pk_f32_fp8(u.x, true);
        acc[0] += f0[0]; acc[1] += f0[1]; acc[2] += f1[0]; acc[3] += f1[1];
    }
    {
        auto f0 = __builtin_amdgcn_cvt_pk_f32_fp8(u.y, false);
        auto f1 = __builtin_amdgcn_cvt_pk_f32_fp8(u.y, true);
        acc[4] += f0[0]; acc[5] += f0[1]; acc[6] += f1[0]; acc[7] += f1[1];
    }
    {
        auto f0 = __builtin_amdgcn_cvt_pk_f32_fp8(u.z, false);
        auto f1 = __builtin_amdgcn_cvt_pk_f32_fp8(u.z, true);
        acc[8] += f0[0]; acc[9] += f0[1]; acc[10] += f1[0]; acc[11] += f1[1];
    }
    {
        auto f0 = __builtin_amdgcn_cvt_pk_f32_fp8(u.w, false);
        auto f1 = __builtin_amdgcn_cvt_pk_f32_fp8(u.w, true);
        acc[12] += f0[0]; acc[13] += f0[1]; acc[14] += f1[0]; acc[15] += f1[1];
    }
    (void)t;
}

// ---------------- utility ---------------------------------------------------
__global__ void zero_kernel(int* __restrict__ p, int n) {
    int i = blockIdx.x * 256 + threadIdx.x;
    if (i < n) p[i] = 0;
}

// ---------------- edge dtype detection (int32 vs int64 storage) -------------
__global__ void detect_kernel(const int* __restrict__ ei, int* __restrict__ mode) {
    __shared__ int any_nz;
    if (threadIdx.x == 0) any_nz = 0;
    __syncthreads();
    int nz = 0;
    for (int i = threadIdx.x; i < 4096; i += 256) nz |= (ei[2 * i + 1] != 0);
    if (nz) atomicOr(&any_nz, 1);
    __syncthreads();
    if (threadIdx.x == 0) *mode = any_nz ? 0 : 1;   // 1 => int64 storage
}

__device__ __forceinline__ int get_row(const int* ei, int e, int m) {
    return m ? ei[2 * e] : ei[e];
}
__device__ __forceinline__ int get_col(const int* ei, int e, int m) {
    return m ? ei[2 * NE + 2 * e] : ei[NE + e];
}

// ---------------- CSR build -------------------------------------------------
__global__ void count_kernel(const int* __restrict__ ei, int* __restrict__ deg,
                             const int* __restrict__ mode) {
    int e = blockIdx.x * 256 + threadIdx.x;
    int m = *mode;
    if (e < NE) atomicAdd(&deg[get_col(ei, e, m)], 1);
}

__global__ void scan1_kernel(const int* __restrict__ deg, int* __restrict__ offs,
                             int* __restrict__ bsums) {
    __shared__ int sd[256];
    int tid = threadIdx.x;
    int base = blockIdx.x * 1024 + tid * 4;
    int v[4]; int s = 0;
#pragma unroll
    for (int k = 0; k < 4; ++k) { v[k] = (base + k < NN) ? deg[base + k] : 0; s += v[k]; }
    sd[tid] = s;
    __syncthreads();
    for (int off = 1; off < 256; off <<= 1) {
        int t = (tid >= off) ? sd[tid - off] : 0;
        __syncthreads();
        sd[tid] += t;
        __syncthreads();
    }
    int excl = sd[tid] - s;
    if (tid == 255) bsums[blockIdx.x] = sd[255];
    int p = excl;
#pragma unroll
    for (int k = 0; k < 4; ++k) {
        if (base + k < NN) offs[base + k] = p;
        p += v[k];
    }
}

__global__ void scan2_kernel(int* __restrict__ bsums, int nb) {
    __shared__ int sd[128];
    int tid = threadIdx.x;
    int v = (tid < nb) ? bsums[tid] : 0;
    sd[tid] = v;
    __syncthreads();
    for (int off = 1; off < 128; off <<= 1) {
        int t = (tid >= off) ? sd[tid - off] : 0;
        __syncthreads();
        sd[tid] += t;
        __syncthreads();
    }
    if (tid < nb) bsums[tid] = sd[tid] - v;   // exclusive
}

__global__ void scan3_kernel(int* __restrict__ offs, const int* __restrict__ bsums,
                             int* __restrict__ cursor) {
    int i = blockIdx.x * 256 + threadIdx.x;
    if (i < NN) {
        int o = offs[i] + bsums[i >> 10];
        offs[i] = o;
        cursor[i] = o;
    }
    if (i == 0) offs[NN] = NE;
}

__global__ void fill_kernel(const int* __restrict__ ei, int* __restrict__ cursor,
                            int* __restrict__ srcs, const int* __restrict__ mode) {
    int e = blockIdx.x * 256 + threadIdx.x;
    int m = *mode;
    if (e < NE) {
        int c = get_col(ei, e, m);
        int p = atomicAdd(&cursor[c], 1);
        srcs[p] = get_row(ei, e, m);
    }
}

// ---------------- phase 1 (MFMA): per-node MLPs -> Q(f32), K(bf16), V(bf16) -
__global__ __launch_bounds__(256) void phase1_kernel(
    const float* __restrict__ feat, const float* __restrict__ Win,
    const float* __restrict__ bin, const float* __restrict__ Wq,
    const float* __restrict__ bq, const float* __restrict__ Wk,
    const float* __restrict__ bk, const float* __restrict__ Wv,
    const float* __restrict__ bv, const float* __restrict__ hopwise,
    float* __restrict__ Qg, unsigned short* __restrict__ Kb,
    unsigned short* __restrict__ Vb, float* __restrict__ out)
{
    __shared__ float xs_all[4][16 * 36];       // 9216 B

    int tid  = threadIdx.x;
    int wid  = tid >> 6;
    int lane = tid & 63;
    int q    = lane >> 4;        // quad 0..3
    int col  = lane & 15;
    int node0 = (blockIdx.x * 4 + wid) * 16;

    v8s wb[4][2];
#pragma unroll
    for (int kk = 0; kk < 4; ++kk)
#pragma unroll
        for (int t = 0; t < 2; ++t)
#pragma unroll
            for (int j = 0; j < 8; ++j)
                wb[kk][t][j] = (short)bf_round(Win[(kk * 32 + q * 8 + j) * CH + t * 16 + col]);

    v8s wq[2], wk[2], wv;
#pragma unroll
    for (int t = 0; t < 2; ++t)
#pragma unroll
        for (int j = 0; j < 8; ++j) {
            wq[t][j] = (short)bf_round(Wq[(q * 8 + j) * CH + t * 16 + col]);
            wk[t][j] = (short)bf_round(Wk[(q * 8 + j) * CH + t * 16 + col]);
        }
#pragma unroll
    for (int j = 0; j < 8; ++j)
        wv[j] = (short)bf_round(Wv[(q * 8 + j) * NC + col]);

    float bin0 = bin[col], bin1 = bin[col + 16];
    float bq0 = bq[col], bq1 = bq[col + 16];
    float bk0 = bk[col], bk1 = bk[col + 16];
    float bv0 = bv[col];
    float hw0 = hopwise[0];

    int nodeA = node0 + col;
    int nclamp = nodeA < NN ? nodeA : NN - 1;
    const float* fr = feat + (size_t)nclamp * F_IN + q * 8;

    v4f acc0 = {0.f, 0.f, 0.f, 0.f}, acc1 = {0.f, 0.f, 0.f, 0.f};
#pragma unroll
    for (int kk = 0; kk < 4; ++kk) {
        float4 a = *(const float4*)(fr + kk * 32);
        float4 b = *(const float4*)(fr + kk * 32 + 4);
        v8s af;
        af[0] = bfq(a.x); af[1] = bfq(a.y); af[2] = bfq(a.z); af[3] = bfq(a.w);
        af[4] = bfq(b.x); af[5] = bfq(b.y); af[6] = bfq(b.z); af[7] = bfq(b.w);
        acc0 = __builtin_amdgcn_mfma_f32_16x16x32_bf16(af, wb[kk][0], acc0, 0, 0, 0);
        acc1 = __builtin_amdgcn_mfma_f32_16x16x32_bf16(af, wb[kk][1], acc1, 0, 0, 0);
    }

    float* xs = xs_all[wid];
#pragma unroll
    for (int r = 0; r < 4; ++r) {
        xs[(q * 4 + r) * 36 + col]      = fmaxf(acc0[r] + bin0, 0.f);
        xs[(q * 4 + r) * 36 + col + 16] = fmaxf(acc1[r] + bin1, 0.f);
    }

    float4 xa = *(const float4*)&xs[col * 36 + q * 8];
    float4 xb = *(const float4*)&xs[col * 36 + q * 8 + 4];
    v8s xf;
    xf[0] = bfq(xa.x); xf[1] = bfq(xa.y); xf[2] = bfq(xa.z); xf[3] = bfq(xa.w);
    xf[4] = bfq(xb.x); xf[5] = bfq(xb.y); xf[6] = bfq(xb.z); xf[7] = bfq(xb.w);

    v4f aq0 = {0.f,0.f,0.f,0.f}, aq1 = {0.f,0.f,0.f,0.f};
    v4f ak0 = {0.f,0.f,0.f,0.f}, ak1 = {0.f,0.f,0.f,0.f};
    v4f av  = {0.f,0.f,0.f,0.f};
    aq0 = __builtin_amdgcn_mfma_f32_16x16x32_bf16(xf, wq[0], aq0, 0, 0, 0);
    aq1 = __builtin_amdgcn_mfma_f32_16x16x32_bf16(xf, wq[1], aq1, 0, 0, 0);
    ak0 = __builtin_amdgcn_mfma_f32_16x16x32_bf16(xf, wk[0], ak0, 0, 0, 0);
    ak1 = __builtin_amdgcn_mfma_f32_16x16x32_bf16(xf, wk[1], ak1, 0, 0, 0);
    av  = __builtin_amdgcn_mfma_f32_16x16x32_bf16(xf, wv,    av,  0, 0, 0);

#pragma unroll
    for (int r = 0; r < 4; ++r) {
        int nd = node0 + 4 * q + r;
        if (nd < NN) {
            float q0 = elu1(aq0[r] + bq0);
            float q1 = elu1(aq1[r] + bq1);
            float k0 = elu1(ak0[r] + bk0);
            float k1 = elu1(ak1[r] + bk1);
            float vv = av[r] + bv0;
            Qg[(size_t)nd * CH + col]      = q0;
            Qg[(size_t)nd * CH + col + 16] = q1;
            Kb[(size_t)nd * CH + col]      = (unsigned short)bf_round(k0);
            Kb[(size_t)nd * CH + col + 16] = (unsigned short)bf_round(k1);
            Vb[(size_t)nd * NC + col]      = (unsigned short)bf_round(vv);
            out[(size_t)nd * NC + col]     = hw0 * vv;
        }
    }
}

// ---------------- fused hop (CB=32): half-wave per edge, 4 rows in flight ---
// M layout per node: 512 fp8 bytes, element f = c*16 + j. Lane l32 owns
// channel c=l32, holding j=0..15 (16 B dwordx4). Half-waves process
// alternating edges; combined via shfl_xor(32) at the end.
template<bool RANK1, bool WRITE>
__global__ __launch_bounds__(256) void hop32_kernel(
    const float* __restrict__ Qg, const unsigned short* __restrict__ Kb,
    const unsigned short* __restrict__ Vb, const unsigned char* __restrict__ Min,
    unsigned char* __restrict__ Mout, unsigned short* __restrict__ Kout,
    const int* __restrict__ offs, const int* __restrict__ srcs,
    const float* __restrict__ hopw, int hop, float* __restrict__ out)
{
    int tid = threadIdx.x;
    int wid = tid >> 6, lane = tid & 63;
    int node = blockIdx.x * 4 + wid;
    if (node >= NN) return;
    int l32  = lane & 31;
    int half = lane >> 5;

    float acc[16];
#pragma unroll
    for (int k = 0; k < 16; ++k) acc[k] = 0.f;
    float kagg = 0.f;

    int s = offs[node], e = offs[node + 1];
    int i = s + half;

    if (RANK1) {
        for (; i + 2 < e; i += 4) {
            int s0 = srcs[i], s1 = srcs[i + 2];
            float k0 = bf_val(Kb[(size_t)s0 * CH + l32]);
            float k1 = bf_val(Kb[(size_t)s1 * CH + l32]);
            uint4 v0a = *(const uint4*)(Vb + (size_t)s0 * NC);
            uint4 v0b = *(const uint4*)(Vb + (size_t)s0 * NC + 8);
            uint4 v1a = *(const uint4*)(Vb + (size_t)s1 * NC);
            uint4 v1b = *(const uint4*)(Vb + (size_t)s1 * NC + 8);
            kagg += k0 + k1;
            acc_kv(acc, k0, v0a, v0b);
            acc_kv(acc, k1, v1a, v1b);
        }
        for (; i < e; i += 2) {
            int s0 = srcs[i];
            float k0 = bf_val(Kb[(size_t)s0 * CH + l32]);
            uint4 v0a = *(const uint4*)(Vb + (size_t)s0 * NC);
            uint4 v0b = *(const uint4*)(Vb + (size_t)s0 * NC + 8);
            kagg += k0;
            acc_kv(acc, k0, v0a, v0b);
        }
    } else {
        for (; i + 2 < e; i += 4) {
            int s0 = srcs[i], s1 = srcs[i + 2];
            uint4 u0 = *(const uint4*)(Min + (size_t)s0 * 512 + l32 * 16);
            uint4 u1 = *(const uint4*)(Min + (size_t)s1 * 512 + l32 * 16);
            float k0 = bf_val(Kb[(size_t)s0 * CH + l32]);
            float k1 = bf_val(Kb[(size_t)s1 * CH + l32]);
            kagg += k0 + k1;
            acc_m16(acc, u0);
            acc_m16(acc, u1);
        }
        for (; i < e; i += 2) {
            int s0 = srcs[i];
            uint4 u0 = *(const uint4*)(Min + (size_t)s0 * 512 + l32 * 16);
            kagg += bf_val(Kb[(size_t)s0 * CH + l32]);
            acc_m16(acc, u0);
        }
    }

    // combine halves
#pragma unroll
    for (int k = 0; k < 16; ++k) acc[k] += __shfl_xor(acc[k], 32);
    kagg += __shfl_xor(kagg, 32);

    float q = Qg[(size_t)node * CH + l32];

    // C = sum_c q[c]*kagg[c]  (reduce within 32-lane half)
    float cp = q * kagg;
#pragma unroll
    for (int st = 1; st <= 16; st <<= 1) cp += __shfl_xor(cp, st);
    float sc = hopw[hop] / (cp + CSTF);

    if (WRITE && lane < 32) {
        Kout[(size_t)node * CH + l32] = (unsigned short)bf_round(kagg);
        uint4 u;
        int p0 = 0, p1 = 0;
        p0 = __builtin_amdgcn_cvt_pk_fp8_f32(cl448(acc[0]),  cl448(acc[1]),  p0, false);
        p0 = __builtin_amdgcn_cvt_pk_fp8_f32(cl448(acc[2]),  cl448(acc[3]),  p0, true);
        u.x = (unsigned int)p0;
        p1 = __builtin_amdgcn_cvt_pk_fp8_f32(cl448(acc[4]),  cl448(acc[5]),  p1, false);
        p1 = __builtin_amdgcn_cvt_pk_fp8_f32(cl448(acc[6]),  cl448(acc[7]),  p1, true);
        u.y = (unsigned int)p1;
        int p2 = 0, p3 = 0;
        p2 = __builtin_amdgcn_cvt_pk_fp8_f32(cl448(acc[8]),  cl448(acc[9]),  p2, false);
        p2 = __builtin_amdgcn_cvt_pk_fp8_f32(cl448(acc[10]), cl448(acc[11]), p2, true);
        u.z = (unsigned int)p2;
        p3 = __builtin_amdgcn_cvt_pk_fp8_f32(cl448(acc[12]), cl448(acc[13]), p3, false);
        p3 = __builtin_amdgcn_cvt_pk_fp8_f32(cl448(acc[14]), cl448(acc[15]), p3, true);
        u.w = (unsigned int)p3;
        *(uint4*)(Mout + (size_t)node * 512 + l32 * 16) = u;
    }

    // H[j] = sum_c q[c]*acc_c[j]
    float h[16];
#pragma unroll
    for (int k = 0; k < 16; ++k) h[k] = q * acc[k];
#pragma unroll
    for (int st = 1; st <= 16; st <<= 1) {
#pragma unroll
        for (int k = 0; k < 16; ++k) h[k] += __shfl_xor(h[k], st);
    }

    if (lane == 0) {
        float4* o = (float4*)(out + (size_t)node * NC);
#pragma unroll
        for (int t = 0; t < 4; ++t) {
            float4 v = o[t];
            v.x += sc * h[4 * t + 0];
            v.y += sc * h[4 * t + 1];
            v.z += sc * h[4 * t + 2];
            v.w += sc * h[4 * t + 3];
            o[t] = v;
        }
    }
}

// ---------------- fallback K propagation (bf16) + sc ------------------------
__global__ __launch_bounds__(256) void kprop_kernel(
    const float* __restrict__ Qg, const unsigned short* __restrict__ Kin,
    unsigned short* __restrict__ Kout, const int* __restrict__ offs,
    const int* __restrict__ srcs, const float* __restrict__ hopw, int hop,
    float* __restrict__ sc)
{
    int tid = threadIdx.x;
    int wid = tid >> 6, lane = tid & 63;
    int half = lane >> 5, c = lane & 31;
    int node = blockIdx.x * 8 + wid * 2 + half;
    if (node >= NN) return;

    float k = 0.f;
    int s = offs[node], e = offs[node + 1];
    for (int i = s; i < e; ++i) k += bf_val(Kin[(size_t)srcs[i] * CH + c]);
    Kout[(size_t)node * CH + c] = (unsigned short)bf_round(k);

    float cp = Qg[(size_t)node * CH + c] * k;
#pragma unroll
    for (int m = 1; m < 32; m <<= 1) cp += __shfl_xor(cp, m, 32);
    if (c == 0) sc[node] = hopw[hop] / (cp + CSTF);
}

// ---------------- fallback chunked hop (CB<32, fp8 M, scbuf scales) ---------
template<int CB, bool RANK1, bool WRITE>
__global__ __launch_bounds__(256) void hopc_kernel(
    const float* __restrict__ Qg, const unsigned short* __restrict__ Kb,
    const unsigned short* __restrict__ Vb, const unsigned char* __restrict__ Min,
    unsigned char* __restrict__ Mout, const int* __restrict__ offs,
    const int* __restrict__ srcs, const float* __restrict__ scbuf,
    int c0, float* __restrict__ out)
{
    constexpr int EPL = CB * 16 / 64;
    constexpr int L   = 16 / EPL;
    int tid = threadIdx.x;
    int wid = tid >> 6, lane = tid & 63;
    int node = blockIdx.x * 4 + wid;
    if (node >= NN) return;

    int jb = EPL * (lane & (L - 1));
    int cl = lane / L;

    float acc[EPL];
#pragma unroll
    for (int k = 0; k < EPL; ++k) acc[k] = 0.f;

    int s = offs[node], e = offs[node + 1];
    for (int i = s; i < e; ++i) {
        int src = srcs[i];
        if (RANK1) {
            float kc = bf_val(Kb[(size_t)src * CH + c0 + cl]);
            const unsigned short* vp = Vb + (size_t)src * NC + jb;
            if (EPL == 8) {
                uint4 u = *(const uint4*)vp;
                acc[0] += kc * bf_lo(u.x); acc[1] += kc * bf_hi(u.x);
                acc[2] += kc * bf_lo(u.y); acc[3] += kc * bf_hi(u.y);
                acc[4] += kc * bf_lo(u.z); acc[5] += kc * bf_hi(u.z);
                acc[6] += kc * bf_lo(u.w); acc[7] += kc * bf_hi(u.w);
            } else if (EPL == 4) {
                uint2 u = *(const uint2*)vp;
                acc[0] += kc * bf_lo(u.x); acc[1] += kc * bf_hi(u.x);
                acc[2] += kc * bf_lo(u.y); acc[3] += kc * bf_hi(u.y);
            } else if (EPL == 2) {
                unsigned int u = *(const unsigned int*)vp;
                acc[0] += kc * bf_lo(u); acc[1] += kc * bf_hi(u);
            } else {
                acc[0] += kc * bf_val(vp[0]);
            }
        } else {
            const unsigned char* mi = Min + (size_t)src * (CB * 16) + lane * EPL;
            if (EPL == 8) {
                uint2 u = *(const uint2*)mi;
                auto f0 = __builtin_amdgcn_cvt_pk_f32_fp8(u.x, false);
                auto f1 = __builtin_amdgcn_cvt_pk_f32_fp8(u.x, true);
                auto f2 = __builtin_amdgcn_cvt_pk_f32_fp8(u.y, false);
                auto f3 = __builtin_amdgcn_cvt_pk_f32_fp8(u.y, true);
                acc[0] += f0[0]; acc[1] += f0[1]; acc[2] += f1[0]; acc[3] += f1[1];
                acc[4] += f2[0]; acc[5] += f2[1]; acc[6] += f3[0]; acc[7] += f3[1];
            } else if (EPL == 4) {
                unsigned int u = *(const unsigned int*)mi;
                auto f0 = __builtin_amdgcn_cvt_pk_f32_fp8(u, false);
                auto f1 = __builtin_amdgcn_cvt_pk_f32_fp8(u, true);
                acc[0] += f0[0]; acc[1] += f0[1]; acc[2] += f1[0]; acc[3] += f1[1];
            } else if (EPL == 2) {
                unsigned int u = *(const unsigned short*)mi;
                auto f0 = __builtin_amdgcn_cvt_pk_f32_fp8(u, false);
                acc[0] += f0[0]; acc[1] += f0[1];
            } else {
                unsigned int u = *mi;
                auto f0 = __builtin_amdgcn_cvt_pk_f32_fp8(u, false);
                acc[0] += f0[0];
            }
        }
    }

    if (WRITE) {
        unsigned char* mo = Mout + (size_t)node * (CB * 16) + lane * EPL;
        if (EPL == 8) {
            int p0 = 0, p1 = 0;
            p0 = __builtin_amdgcn_cvt_pk_fp8_f32(cl448(acc[0]), cl448(acc[1]), p0, false);
            p0 = __builtin_amdgcn_cvt_pk_fp8_f32(cl448(acc[2]), cl448(acc[3]), p0, true);
            p1 = __builtin_amdgcn_cvt_pk_fp8_f32(cl448(acc[4]), cl448(acc[5]), p1, false);
            p1 = __builtin_amdgcn_cvt_pk_fp8_f32(cl448(acc[6]), cl448(acc[7]), p1, true);
            uint2 u; u.x = (unsigned int)p0; u.y = (unsigned int)p1;
            *(uint2*)mo = u;
        } else if (EPL == 4) {
            int p0 = 0;
            p0 = __builtin_amdgcn_cvt_pk_fp8_f32(cl448(acc[0]), cl448(acc[1]), p0, false);
            p0 = __builtin_amdgcn_cvt_pk_fp8_f32(cl448(acc[2]), cl448(acc[3]), p0, true);
            *(unsigned int*)mo = (unsigned int)p0;
        } else if (EPL == 2) {
            int p0 = __builtin_amdgcn_cvt_pk_fp8_f32(cl448(acc[0]), cl448(acc[1]), 0, false);
            *(unsigned short*)mo = (unsigned short)(p0 & 0xffff);
        } else {
            int p0 = __builtin_amdgcn_cvt_pk_fp8_f32(cl448(acc[0]), 0.f, 0, false);
            *mo = (unsigned char)(p0 & 0xff);
        }
    }

    float q = Qg[(size_t)node * CH + c0 + cl];
    float h[EPL];
#pragma unroll
    for (int k = 0; k < EPL; ++k) h[k] = q * acc[k];
#pragma unroll
    for (int st = L; st < 64; st <<= 1) {
#pragma unroll
        for (int k = 0; k < EPL; ++k) h[k] += __shfl_xor(h[k], st);
    }
    if (lane < L) {
        float scn = scbuf[node];
#pragma unroll
        for (int k = 0; k < EPL; ++k)
            out[(size_t)node * NC + jb + k] += scn * h[k];
    }
}

template<int CB>
static void run_chunks(const float* Qg, const unsigned short* K0b,
                       const unsigned short* Vb, unsigned char* MA,
                       unsigned char* MB, const int* offs, const int* srcs,
                       const float* sc1, const float* sc2, const float* sc3,
                       float* out, hipStream_t stream)
{
    for (int c0 = 0; c0 < CH; c0 += CB) {
        hopc_kernel<CB, true,  true ><<<25000, 256, 0, stream>>>(Qg, K0b, Vb, nullptr, MA, offs, srcs, sc1, c0, out);
        hopc_kernel<CB, false, true ><<<25000, 256, 0, stream>>>(Qg, K0b, Vb, MA, MB, offs, srcs, sc2, c0, out);
        hopc_kernel<CB, false, false><<<25000, 256, 0, stream>>>(Qg, K0b, Vb, MB, nullptr, offs, srcs, sc3, c0, out);
    }
}

// ---------------- launch ----------------------------------------------------
extern "C" void kernel_launch(void* const* d_in, const int* in_sizes, int n_in,
                              void* d_out, int out_size, void* d_ws, size_t ws_size,
                              hipStream_t stream) {
    const float* feat = (const float*)d_in[0];
    const int*   ei   = (const int*)d_in[1];
    const float* Win  = (const float*)d_in[2];
    const float* bin  = (const float*)d_in[3];
    const float* Wq   = (const float*)d_in[4];
    const float* bq   = (const float*)d_in[5];
    const float* Wk   = (const float*)d_in[6];
    const float* bk   = (const float*)d_in[7];
    const float* Wv   = (const float*)d_in[8];
    const float* bv   = (const float*)d_in[9];
    const float* hopw = (const float*)d_in[10];
    float* out = (float*)d_out;

    char* ws = (char*)d_ws;
    size_t off = 0;
    auto alloc = [&](size_t bytes) -> void* {
        void* p = ws + off;
        off += (bytes + 255) & ~(size_t)255;
        return p;
    };
    float*          Qg  = (float*)alloc((size_t)NN * CH * 4);
    unsigned short* K0b = (unsigned short*)alloc((size_t)NN * CH * 2);
    unsigned short* K1b = (unsigned short*)alloc((size_t)NN * CH * 2);
    unsigned short* K2b = (unsigned short*)alloc((size_t)NN * CH * 2);
    unsigned short* K3b = (unsigned short*)alloc((size_t)NN * CH * 2);
    unsigned short* Vb  = (unsigned short*)alloc((size_t)NN * NC * 2);
    float* sc1 = (float*)alloc((size_t)NN * 4);
    float* sc2 = (float*)alloc((size_t)NN * 4);
    float* sc3 = (float*)alloc((size_t)NN * 4);
    int*   deg = (int*)alloc((size_t)NN * 4);
    int*   offs   = (int*)alloc((size_t)(NN + 1) * 4);
    int*   cursor = (int*)alloc((size_t)NN * 4);
    int*   bsums  = (int*)alloc(512);
    int*   mode   = (int*)alloc(4);
    int*   srcs   = (int*)alloc((size_t)NE * 4);
    size_t fixed = off;

    auto mbytes = [](int cb) { return (size_t)NN * cb * 16; };
    int CB = 4;
    if      (ws_size >= fixed + 2 * mbytes(32) + 512) CB = 32;
    else if (ws_size >= fixed + 2 * mbytes(16) + 512) CB = 16;
    else if (ws_size >= fixed + 2 * mbytes(8)  + 512) CB = 8;
    unsigned char* MA = (unsigned char*)alloc(mbytes(CB));
    unsigned char* MB = (unsigned char*)alloc(mbytes(CB));

    // CSR build
    zero_kernel<<<(NN + 255) / 256, 256, 0, stream>>>(deg, NN);
    detect_kernel<<<1, 256, 0, stream>>>(ei, mode);
    count_kernel<<<(NE + 255) / 256, 256, 0, stream>>>(ei, deg, mode);
    int nb = (NN + 1023) / 1024;
    scan1_kernel<<<nb, 256, 0, stream>>>(deg, offs, bsums);
    scan2_kernel<<<1, 128, 0, stream>>>(bsums, nb);
    scan3_kernel<<<(NN + 255) / 256, 256, 0, stream>>>(offs, bsums, cursor);
    fill_kernel<<<(NE + 255) / 256, 256, 0, stream>>>(ei, cursor, srcs, mode);

    // node-wise MLPs (MFMA)
    phase1_kernel<<<1563, 256, 0, stream>>>(feat, Win, bin, Wq, bq, Wk, bk, Wv, bv,
                                            hopw, Qg, K0b, Vb, out);

    if (CB == 32) {
        hop32_kernel<true,  true ><<<25000, 256, 0, stream>>>(Qg, K0b, Vb, nullptr, MA, K1b, offs, srcs, hopw, 1, out);
        hop32_kernel<false, true ><<<25000, 256, 0, stream>>>(Qg, K1b, Vb, MA, MB, K2b, offs, srcs, hopw, 2, out);
        hop32_kernel<false, false><<<25000, 256, 0, stream>>>(Qg, K2b, Vb, MB, nullptr, nullptr, offs, srcs, hopw, 3, out);
    } else {
        kprop_kernel<<<12500, 256, 0, stream>>>(Qg, K0b, K1b, offs, srcs, hopw, 1, sc1);
        kprop_kernel<<<12500, 256, 0, stream>>>(Qg, K1b, K2b, offs, srcs, hopw, 2, sc2);
        kprop_kernel<<<12500, 256, 0, stream>>>(Qg, K2b, K3b, offs, srcs, hopw, 3, sc3);
        if      (CB == 16) run_chunks<16>(Qg, K0b, Vb, MA, MB, offs, srcs, sc1, sc2, sc3, out, stream);
        else if (CB == 8)  run_chunks<8> (Qg, K0b, Vb, MA, MB, offs, srcs, sc1, sc2, sc3, out, stream);
        else               run_chunks<4> (Qg, K0b, Vb, MA, MB, offs, srcs, sc1, sc2, sc3, out, stream);
    }
}

// Round 8
// 421.746 us; speedup vs baseline: 2.7346x; 1.2752x over previous
//
#include <hip/hip_runtime.h>
#include <math.h>

#define NN 100000
#define NE 800000
#define F_IN 128
#define CH 32
#define NC 16
#define CSTF 1e-5f

typedef float v4f __attribute__((ext_vector_type(4)));
typedef short v8s __attribute__((ext_vector_type(8)));

// ---------------- bf16 helpers ----------------------------------------------
__device__ __forceinline__ float bf_lo(unsigned int u) {
    unsigned int t = u << 16;
    return __builtin_bit_cast(float, t);
}
__device__ __forceinline__ float bf_hi(unsigned int u) {
    unsigned int t = u & 0xffff0000u;
    return __builtin_bit_cast(float, t);
}
__device__ __forceinline__ float bf_val(unsigned short v) {
    unsigned int t = ((unsigned int)v) << 16;
    return __builtin_bit_cast(float, t);
}
__device__ __forceinline__ unsigned int bf_round(float a) {
    unsigned int ua = __builtin_bit_cast(unsigned int, a);
    return (ua + 0x7fffu + ((ua >> 16) & 1u)) >> 16;     // RNE, a finite
}
__device__ __forceinline__ short bfq(float a) {
    unsigned int ua = __builtin_bit_cast(unsigned int, a);
    return (short)((ua + 0x8000u) >> 16);
}

// fp8 e4m3 clamp: avoid NaN on overflow (max normal = 448)
__device__ __forceinline__ float cl448(float a) {
    return fminf(fmaxf(a, -448.f), 448.f);
}

__device__ __forceinline__ float elu1(float x) {
    return 1.f + ((x > 0.f) ? x : (expf(x) - 1.f));
}

// accumulate 8 fp8 values from a uint2
__device__ __forceinline__ void acc_m8(float* acc, uint2 u) {
    auto f0 = __builtin_amdgcn_cvt_pk_f32_fp8(u.x, false);
    auto f1 = __builtin_amdgcn_cvt_pk_f32_fp8(u.x, true);
    auto f2 = __builtin_amdgcn_cvt_pk_f32_fp8(u.y, false);
    auto f3 = __builtin_amdgcn_cvt_pk_f32_fp8(u.y, true);
    acc[0] += f0[0]; acc[1] += f0[1]; acc[2] += f1[0]; acc[3] += f1[1];
    acc[4] += f2[0]; acc[5] += f2[1]; acc[6] += f3[0]; acc[7] += f3[1];
}
// accumulate 8 bf16 V values scaled by kc
__device__ __forceinline__ void acc_kv8(float* acc, float kc, uint4 v) {
    acc[0] += kc * bf_lo(v.x); acc[1] += kc * bf_hi(v.x);
    acc[2] += kc * bf_lo(v.y); acc[3] += kc * bf_hi(v.y);
    acc[4] += kc * bf_lo(v.z); acc[5] += kc * bf_hi(v.z);
    acc[6] += kc * bf_lo(v.w); acc[7] += kc * bf_hi(v.w);
}

// ---------------- utility ---------------------------------------------------
__global__ void zero_kernel(int* __restrict__ p, int n) {
    int i = blockIdx.x * 256 + threadIdx.x;
    if (i < n) p[i] = 0;
}

// ---------------- edge dtype detection (int32 vs int64 storage) -------------
__global__ void detect_kernel(const int* __restrict__ ei, int* __restrict__ mode) {
    __shared__ int any_nz;
    if (threadIdx.x == 0) any_nz = 0;
    __syncthreads();
    int nz = 0;
    for (int i = threadIdx.x; i < 4096; i += 256) nz |= (ei[2 * i + 1] != 0);
    if (nz) atomicOr(&any_nz, 1);
    __syncthreads();
    if (threadIdx.x == 0) *mode = any_nz ? 0 : 1;   // 1 => int64 storage
}

__device__ __forceinline__ int get_row(const int* ei, int e, int m) {
    return m ? ei[2 * e] : ei[e];
}
__device__ __forceinline__ int get_col(const int* ei, int e, int m) {
    return m ? ei[2 * NE + 2 * e] : ei[NE + e];
}

// ---------------- CSR build -------------------------------------------------
__global__ void count_kernel(const int* __restrict__ ei, int* __restrict__ deg,
                             const int* __restrict__ mode) {
    int e = blockIdx.x * 256 + threadIdx.x;
    int m = *mode;
    if (e < NE) atomicAdd(&deg[get_col(ei, e, m)], 1);
}

__global__ void scan1_kernel(const int* __restrict__ deg, int* __restrict__ offs,
                             int* __restrict__ bsums) {
    __shared__ int sd[256];
    int tid = threadIdx.x;
    int base = blockIdx.x * 1024 + tid * 4;
    int v[4]; int s = 0;
#pragma unroll
    for (int k = 0; k < 4; ++k) { v[k] = (base + k < NN) ? deg[base + k] : 0; s += v[k]; }
    sd[tid] = s;
    __syncthreads();
    for (int off = 1; off < 256; off <<= 1) {
        int t = (tid >= off) ? sd[tid - off] : 0;
        __syncthreads();
        sd[tid] += t;
        __syncthreads();
    }
    int excl = sd[tid] - s;
    if (tid == 255) bsums[blockIdx.x] = sd[255];
    int p = excl;
#pragma unroll
    for (int k = 0; k < 4; ++k) {
        if (base + k < NN) offs[base + k] = p;
        p += v[k];
    }
}

__global__ void scan2_kernel(int* __restrict__ bsums, int nb) {
    __shared__ int sd[128];
    int tid = threadIdx.x;
    int v = (tid < nb) ? bsums[tid] : 0;
    sd[tid] = v;
    __syncthreads();
    for (int off = 1; off < 128; off <<= 1) {
        int t = (tid >= off) ? sd[tid - off] : 0;
        __syncthreads();
        sd[tid] += t;
        __syncthreads();
    }
    if (tid < nb) bsums[tid] = sd[tid] - v;   // exclusive
}

__global__ void scan3_kernel(int* __restrict__ offs, const int* __restrict__ bsums,
                             int* __restrict__ cursor) {
    int i = blockIdx.x * 256 + threadIdx.x;
    if (i < NN) {
        int o = offs[i] + bsums[i >> 10];
        offs[i] = o;
        cursor[i] = o;
    }
    if (i == 0) offs[NN] = NE;
}

__global__ void fill_kernel(const int* __restrict__ ei, int* __restrict__ cursor,
                            int* __restrict__ srcs, const int* __restrict__ mode) {
    int e = blockIdx.x * 256 + threadIdx.x;
    int m = *mode;
    if (e < NE) {
        int c = get_col(ei, e, m);
        int p = atomicAdd(&cursor[c], 1);
        srcs[p] = get_row(ei, e, m);
    }
}

// ---------------- phase 1 (MFMA): per-node MLPs -> Q(f32), K(bf16), V(bf16) -
__global__ __launch_bounds__(256) void phase1_kernel(
    const float* __restrict__ feat, const float* __restrict__ Win,
    const float* __restrict__ bin, const float* __restrict__ Wq,
    const float* __restrict__ bq, const float* __restrict__ Wk,
    const float* __restrict__ bk, const float* __restrict__ Wv,
    const float* __restrict__ bv, const float* __restrict__ hopwise,
    float* __restrict__ Qg, unsigned short* __restrict__ Kb,
    unsigned short* __restrict__ Vb, float* __restrict__ out)
{
    __shared__ float xs_all[4][16 * 36];       // 9216 B

    int tid  = threadIdx.x;
    int wid  = tid >> 6;
    int lane = tid & 63;
    int q    = lane >> 4;        // quad 0..3
    int col  = lane & 15;
    int node0 = (blockIdx.x * 4 + wid) * 16;

    v8s wb[4][2];
#pragma unroll
    for (int kk = 0; kk < 4; ++kk)
#pragma unroll
        for (int t = 0; t < 2; ++t)
#pragma unroll
            for (int j = 0; j < 8; ++j)
                wb[kk][t][j] = (short)bf_round(Win[(kk * 32 + q * 8 + j) * CH + t * 16 + col]);

    v8s wq[2], wk[2], wv;
#pragma unroll
    for (int t = 0; t < 2; ++t)
#pragma unroll
        for (int j = 0; j < 8; ++j) {
            wq[t][j] = (short)bf_round(Wq[(q * 8 + j) * CH + t * 16 + col]);
            wk[t][j] = (short)bf_round(Wk[(q * 8 + j) * CH + t * 16 + col]);
        }
#pragma unroll
    for (int j = 0; j < 8; ++j)
        wv[j] = (short)bf_round(Wv[(q * 8 + j) * NC + col]);

    float bin0 = bin[col], bin1 = bin[col + 16];
    float bq0 = bq[col], bq1 = bq[col + 16];
    float bk0 = bk[col], bk1 = bk[col + 16];
    float bv0 = bv[col];
    float hw0 = hopwise[0];

    int nodeA = node0 + col;
    int nclamp = nodeA < NN ? nodeA : NN - 1;
    const float* fr = feat + (size_t)nclamp * F_IN + q * 8;

    v4f acc0 = {0.f, 0.f, 0.f, 0.f}, acc1 = {0.f, 0.f, 0.f, 0.f};
#pragma unroll
    for (int kk = 0; kk < 4; ++kk) {
        float4 a = *(const float4*)(fr + kk * 32);
        float4 b = *(const float4*)(fr + kk * 32 + 4);
        v8s af;
        af[0] = bfq(a.x); af[1] = bfq(a.y); af[2] = bfq(a.z); af[3] = bfq(a.w);
        af[4] = bfq(b.x); af[5] = bfq(b.y); af[6] = bfq(b.z); af[7] = bfq(b.w);
        acc0 = __builtin_amdgcn_mfma_f32_16x16x32_bf16(af, wb[kk][0], acc0, 0, 0, 0);
        acc1 = __builtin_amdgcn_mfma_f32_16x16x32_bf16(af, wb[kk][1], acc1, 0, 0, 0);
    }

    float* xs = xs_all[wid];
#pragma unroll
    for (int r = 0; r < 4; ++r) {
        xs[(q * 4 + r) * 36 + col]      = fmaxf(acc0[r] + bin0, 0.f);
        xs[(q * 4 + r) * 36 + col + 16] = fmaxf(acc1[r] + bin1, 0.f);
    }

    float4 xa = *(const float4*)&xs[col * 36 + q * 8];
    float4 xb = *(const float4*)&xs[col * 36 + q * 8 + 4];
    v8s xf;
    xf[0] = bfq(xa.x); xf[1] = bfq(xa.y); xf[2] = bfq(xa.z); xf[3] = bfq(xa.w);
    xf[4] = bfq(xb.x); xf[5] = bfq(xb.y); xf[6] = bfq(xb.z); xf[7] = bfq(xb.w);

    v4f aq0 = {0.f,0.f,0.f,0.f}, aq1 = {0.f,0.f,0.f,0.f};
    v4f ak0 = {0.f,0.f,0.f,0.f}, ak1 = {0.f,0.f,0.f,0.f};
    v4f av  = {0.f,0.f,0.f,0.f};
    aq0 = __builtin_amdgcn_mfma_f32_16x16x32_bf16(xf, wq[0], aq0, 0, 0, 0);
    aq1 = __builtin_amdgcn_mfma_f32_16x16x32_bf16(xf, wq[1], aq1, 0, 0, 0);
    ak0 = __builtin_amdgcn_mfma_f32_16x16x32_bf16(xf, wk[0], ak0, 0, 0, 0);
    ak1 = __builtin_amdgcn_mfma_f32_16x16x32_bf16(xf, wk[1], ak1, 0, 0, 0);
    av  = __builtin_amdgcn_mfma_f32_16x16x32_bf16(xf, wv,    av,  0, 0, 0);

#pragma unroll
    for (int r = 0; r < 4; ++r) {
        int nd = node0 + 4 * q + r;
        if (nd < NN) {
            float q0 = elu1(aq0[r] + bq0);
            float q1 = elu1(aq1[r] + bq1);
            float k0 = elu1(ak0[r] + bk0);
            float k1 = elu1(ak1[r] + bk1);
            float vv = av[r] + bv0;
            Qg[(size_t)nd * CH + col]      = q0;
            Qg[(size_t)nd * CH + col + 16] = q1;
            Kb[(size_t)nd * CH + col]      = (unsigned short)bf_round(k0);
            Kb[(size_t)nd * CH + col + 16] = (unsigned short)bf_round(k1);
            Vb[(size_t)nd * NC + col]      = (unsigned short)bf_round(vv);
            out[(size_t)nd * NC + col]     = hw0 * vv;
        }
    }
}

// ---------------- fused hop: full wave per edge, LDS-transpose epilogue -----
// M row per node: 512 fp8 bytes, element f = c*16 + j. Lane owns (c=lane&31,
// jh=lane>>5), holding j = jh*8..jh*8+7 (8 B uint2). Unroll x4 edges.
// Epilogue: scale acc by q, LDS transpose (stride 17, 2-way = free), 8-read
// column sums + 2 shfl -> H; cp via 5 shfl. ~23 LDS-pipe ops vs ~102 shfl.
template<bool RANK1, bool WRITE>
__global__ __launch_bounds__(256) void hop64_kernel(
    const float* __restrict__ Qg, const unsigned short* __restrict__ Kb,
    const unsigned short* __restrict__ Vb, const unsigned char* __restrict__ Min,
    unsigned char* __restrict__ Mout, unsigned short* __restrict__ Kout,
    const int* __restrict__ offs, const int* __restrict__ srcs,
    const float* __restrict__ hopw, int hop, float* __restrict__ out)
{
    __shared__ float T_all[4][32 * 17];        // 8704 B

    int tid  = threadIdx.x;
    int wid  = tid >> 6;
    int lane = tid & 63;
    int node = __builtin_amdgcn_readfirstlane(blockIdx.x * 4 + wid);  // NN%4==0
    int c  = lane & 31;
    int jh = lane >> 5;

    float acc[8];
#pragma unroll
    for (int k = 0; k < 8; ++k) acc[k] = 0.f;
    float kagg = 0.f;

    int s = offs[node], e = offs[node + 1];
    int i = s;
    if (RANK1) {
        for (; i + 3 < e; i += 4) {
            int s0 = srcs[i], s1 = srcs[i+1], s2 = srcs[i+2], s3 = srcs[i+3];
            float k0 = bf_val(Kb[(size_t)s0 * CH + c]);
            float k1 = bf_val(Kb[(size_t)s1 * CH + c]);
            float k2 = bf_val(Kb[(size_t)s2 * CH + c]);
            float k3 = bf_val(Kb[(size_t)s3 * CH + c]);
            uint4 v0 = *(const uint4*)(Vb + (size_t)s0 * NC + jh * 8);
            uint4 v1 = *(const uint4*)(Vb + (size_t)s1 * NC + jh * 8);
            uint4 v2 = *(const uint4*)(Vb + (size_t)s2 * NC + jh * 8);
            uint4 v3 = *(const uint4*)(Vb + (size_t)s3 * NC + jh * 8);
            kagg += (k0 + k1) + (k2 + k3);
            acc_kv8(acc, k0, v0); acc_kv8(acc, k1, v1);
            acc_kv8(acc, k2, v2); acc_kv8(acc, k3, v3);
        }
        for (; i < e; ++i) {
            int s0 = srcs[i];
            float k0 = bf_val(Kb[(size_t)s0 * CH + c]);
            uint4 v0 = *(const uint4*)(Vb + (size_t)s0 * NC + jh * 8);
            kagg += k0;
            acc_kv8(acc, k0, v0);
        }
    } else {
        for (; i + 3 < e; i += 4) {
            int s0 = srcs[i], s1 = srcs[i+1], s2 = srcs[i+2], s3 = srcs[i+3];
            uint2 u0 = *(const uint2*)(Min + (size_t)s0 * 512 + c * 16 + jh * 8);
            uint2 u1 = *(const uint2*)(Min + (size_t)s1 * 512 + c * 16 + jh * 8);
            uint2 u2 = *(const uint2*)(Min + (size_t)s2 * 512 + c * 16 + jh * 8);
            uint2 u3 = *(const uint2*)(Min + (size_t)s3 * 512 + c * 16 + jh * 8);
            float k0 = bf_val(Kb[(size_t)s0 * CH + c]);
            float k1 = bf_val(Kb[(size_t)s1 * CH + c]);
            float k2 = bf_val(Kb[(size_t)s2 * CH + c]);
            float k3 = bf_val(Kb[(size_t)s3 * CH + c]);
            kagg += (k0 + k1) + (k2 + k3);
            acc_m8(acc, u0); acc_m8(acc, u1);
            acc_m8(acc, u2); acc_m8(acc, u3);
        }
        for (; i < e; ++i) {
            int s0 = srcs[i];
            uint2 u0 = *(const uint2*)(Min + (size_t)s0 * 512 + c * 16 + jh * 8);
            kagg += bf_val(Kb[(size_t)s0 * CH + c]);
            acc_m8(acc, u0);
        }
    }

    float q = Qg[(size_t)node * CH + c];

    if (WRITE) {
        if (lane < 32)
            Kout[(size_t)node * CH + c] = (unsigned short)bf_round(kagg);
        int p0 = 0, p1 = 0;
        p0 = __builtin_amdgcn_cvt_pk_fp8_f32(cl448(acc[0]), cl448(acc[1]), p0, false);
        p0 = __builtin_amdgcn_cvt_pk_fp8_f32(cl448(acc[2]), cl448(acc[3]), p0, true);
        p1 = __builtin_amdgcn_cvt_pk_fp8_f32(cl448(acc[4]), cl448(acc[5]), p1, false);
        p1 = __builtin_amdgcn_cvt_pk_fp8_f32(cl448(acc[6]), cl448(acc[7]), p1, true);
        uint2 u; u.x = (unsigned int)p0; u.y = (unsigned int)p1;
        *(uint2*)(Mout + (size_t)node * 512 + c * 16 + jh * 8) = u;
    }

    // cp = Q . K_agg  (halves hold identical kagg; reduce within 32)
    float cpv = q * kagg;
#pragma unroll
    for (int st = 1; st <= 16; st <<= 1) cpv += __shfl_xor(cpv, st);
    float sc = hopw[hop] / (cpv + CSTF);

    // H[j] = sum_c q_c * acc_c[j] via LDS transpose (stride 17: 2-way free)
    float* T = T_all[wid];
#pragma unroll
    for (int t = 0; t < 8; ++t)
        T[c * 17 + jh * 8 + t] = q * acc[t];
    asm volatile("" ::: "memory");
    int j2 = lane & 15, cg = lane >> 4;
    float part = 0.f;
#pragma unroll
    for (int t = 0; t < 8; ++t)
        part += T[(cg * 8 + t) * 17 + j2];
    part += __shfl_xor(part, 16);
    part += __shfl_xor(part, 32);

    if (lane < 16)
        out[(size_t)node * NC + lane] += sc * part;
}

// ---------------- fallback K propagation (bf16) + sc ------------------------
__global__ __launch_bounds__(256) void kprop_kernel(
    const float* __restrict__ Qg, const unsigned short* __restrict__ Kin,
    unsigned short* __restrict__ Kout, const int* __restrict__ offs,
    const int* __restrict__ srcs, const float* __restrict__ hopw, int hop,
    float* __restrict__ sc)
{
    int tid = threadIdx.x;
    int wid = tid >> 6, lane = tid & 63;
    int half = lane >> 5, c = lane & 31;
    int node = blockIdx.x * 8 + wid * 2 + half;
    if (node >= NN) return;

    float k = 0.f;
    int s = offs[node], e = offs[node + 1];
    for (int i = s; i < e; ++i) k += bf_val(Kin[(size_t)srcs[i] * CH + c]);
    Kout[(size_t)node * CH + c] = (unsigned short)bf_round(k);

    float cp = Qg[(size_t)node * CH + c] * k;
#pragma unroll
    for (int m = 1; m < 32; m <<= 1) cp += __shfl_xor(cp, m, 32);
    if (c == 0) sc[node] = hopw[hop] / (cp + CSTF);
}

// ---------------- fallback chunked hop (CB<32, fp8 M, scbuf scales) ---------
template<int CB, bool RANK1, bool WRITE>
__global__ __launch_bounds__(256) void hopc_kernel(
    const float* __restrict__ Qg, const unsigned short* __restrict__ Kb,
    const unsigned short* __restrict__ Vb, const unsigned char* __restrict__ Min,
    unsigned char* __restrict__ Mout, const int* __restrict__ offs,
    const int* __restrict__ srcs, const float* __restrict__ scbuf,
    int c0, float* __restrict__ out)
{
    constexpr int EPL = CB * 16 / 64;
    constexpr int L   = 16 / EPL;
    int tid = threadIdx.x;
    int wid = tid >> 6, lane = tid & 63;
    int node = blockIdx.x * 4 + wid;
    if (node >= NN) return;

    int jb = EPL * (lane & (L - 1));
    int cl = lane / L;

    float acc[EPL];
#pragma unroll
    for (int k = 0; k < EPL; ++k) acc[k] = 0.f;

    int s = offs[node], e = offs[node + 1];
    for (int i = s; i < e; ++i) {
        int src = srcs[i];
        if (RANK1) {
            float kc = bf_val(Kb[(size_t)src * CH + c0 + cl]);
            const unsigned short* vp = Vb + (size_t)src * NC + jb;
            if (EPL == 8) {
                uint4 u = *(const uint4*)vp;
                acc[0] += kc * bf_lo(u.x); acc[1] += kc * bf_hi(u.x);
                acc[2] += kc * bf_lo(u.y); acc[3] += kc * bf_hi(u.y);
                acc[4] += kc * bf_lo(u.z); acc[5] += kc * bf_hi(u.z);
                acc[6] += kc * bf_lo(u.w); acc[7] += kc * bf_hi(u.w);
            } else if (EPL == 4) {
                uint2 u = *(const uint2*)vp;
                acc[0] += kc * bf_lo(u.x); acc[1] += kc * bf_hi(u.x);
                acc[2] += kc * bf_lo(u.y); acc[3] += kc * bf_hi(u.y);
            } else if (EPL == 2) {
                unsigned int u = *(const unsigned int*)vp;
                acc[0] += kc * bf_lo(u); acc[1] += kc * bf_hi(u);
            } else {
                acc[0] += kc * bf_val(vp[0]);
            }
        } else {
            const unsigned char* mi = Min + (size_t)src * (CB * 16) + lane * EPL;
            if (EPL == 8) {
                uint2 u = *(const uint2*)mi;
                acc_m8(acc, u);
            } else if (EPL == 4) {
                unsigned int u = *(const unsigned int*)mi;
                auto f0 = __builtin_amdgcn_cvt_pk_f32_fp8(u, false);
                auto f1 = __builtin_amdgcn_cvt_pk_f32_fp8(u, true);
                acc[0] += f0[0]; acc[1] += f0[1]; acc[2] += f1[0]; acc[3] += f1[1];
            } else if (EPL == 2) {
                unsigned int u = *(const unsigned short*)mi;
                auto f0 = __builtin_amdgcn_cvt_pk_f32_fp8(u, false);
                acc[0] += f0[0]; acc[1] += f0[1];
            } else {
                unsigned int u = *mi;
                auto f0 = __builtin_amdgcn_cvt_pk_f32_fp8(u, false);
                acc[0] += f0[0];
            }
        }
    }

    if (WRITE) {
        unsigned char* mo = Mout + (size_t)node * (CB * 16) + lane * EPL;
        if (EPL == 8) {
            int p0 = 0, p1 = 0;
            p0 = __builtin_amdgcn_cvt_pk_fp8_f32(cl448(acc[0]), cl448(acc[1]), p0, false);
            p0 = __builtin_amdgcn_cvt_pk_fp8_f32(cl448(acc[2]), cl448(acc[3]), p0, true);
            p1 = __builtin_amdgcn_cvt_pk_fp8_f32(cl448(acc[4]), cl448(acc[5]), p1, false);
            p1 = __builtin_amdgcn_cvt_pk_fp8_f32(cl448(acc[6]), cl448(acc[7]), p1, true);
            uint2 u; u.x = (unsigned int)p0; u.y = (unsigned int)p1;
            *(uint2*)mo = u;
        } else if (EPL == 4) {
            int p0 = 0;
            p0 = __builtin_amdgcn_cvt_pk_fp8_f32(cl448(acc[0]), cl448(acc[1]), p0, false);
            p0 = __builtin_amdgcn_cvt_pk_fp8_f32(cl448(acc[2]), cl448(acc[3]), p0, true);
            *(unsigned int*)mo = (unsigned int)p0;
        } else if (EPL == 2) {
            int p0 = __builtin_amdgcn_cvt_pk_fp8_f32(cl448(acc[0]), cl448(acc[1]), 0, false);
            *(unsigned short*)mo = (unsigned short)(p0 & 0xffff);
        } else {
            int p0 = __builtin_amdgcn_cvt_pk_fp8_f32(cl448(acc[0]), 0.f, 0, false);
            *mo = (unsigned char)(p0 & 0xff);
        }
    }

    float q = Qg[(size_t)node * CH + c0 + cl];
    float h[EPL];
#pragma unroll
    for (int k = 0; k < EPL; ++k) h[k] = q * acc[k];
#pragma unroll
    for (int st = L; st < 64; st <<= 1) {
#pragma unroll
        for (int k = 0; k < EPL; ++k) h[k] += __shfl_xor(h[k], st);
    }
    if (lane < L) {
        float scn = scbuf[node];
#pragma unroll
        for (int k = 0; k < EPL; ++k)
            out[(size_t)node * NC + jb + k] += scn * h[k];
    }
}

template<int CB>
static void run_chunks(const float* Qg, const unsigned short* K0b,
                       const unsigned short* Vb, unsigned char* MA,
                       unsigned char* MB, const int* offs, const int* srcs,
                       const float* sc1, const float* sc2, const float* sc3,
                       float* out, hipStream_t stream)
{
    for (int c0 = 0; c0 < CH; c0 += CB) {
        hopc_kernel<CB, true,  true ><<<25000, 256, 0, stream>>>(Qg, K0b, Vb, nullptr, MA, offs, srcs, sc1, c0, out);
        hopc_kernel<CB, false, true ><<<25000, 256, 0, stream>>>(Qg, K0b, Vb, MA, MB, offs, srcs, sc2, c0, out);
        hopc_kernel<CB, false, false><<<25000, 256, 0, stream>>>(Qg, K0b, Vb, MB, nullptr, offs, srcs, sc3, c0, out);
    }
}

// ---------------- launch ----------------------------------------------------
extern "C" void kernel_launch(void* const* d_in, const int* in_sizes, int n_in,
                              void* d_out, int out_size, void* d_ws, size_t ws_size,
                              hipStream_t stream) {
    const float* feat = (const float*)d_in[0];
    const int*   ei   = (const int*)d_in[1];
    const float* Win  = (const float*)d_in[2];
    const float* bin  = (const float*)d_in[3];
    const float* Wq   = (const float*)d_in[4];
    const float* bq   = (const float*)d_in[5];
    const float* Wk   = (const float*)d_in[6];
    const float* bk   = (const float*)d_in[7];
    const float* Wv   = (const float*)d_in[8];
    const float* bv   = (const float*)d_in[9];
    const float* hopw = (const float*)d_in[10];
    float* out = (float*)d_out;

    char* ws = (char*)d_ws;
    size_t off = 0;
    auto alloc = [&](size_t bytes) -> void* {
        void* p = ws + off;
        off += (bytes + 255) & ~(size_t)255;
        return p;
    };
    float*          Qg  = (float*)alloc((size_t)NN * CH * 4);
    unsigned short* K0b = (unsigned short*)alloc((size_t)NN * CH * 2);
    unsigned short* K1b = (unsigned short*)alloc((size_t)NN * CH * 2);
    unsigned short* K2b = (unsigned short*)alloc((size_t)NN * CH * 2);
    unsigned short* K3b = (unsigned short*)alloc((size_t)NN * CH * 2);
    unsigned short* Vb  = (unsigned short*)alloc((size_t)NN * NC * 2);
    float* sc1 = (float*)alloc((size_t)NN * 4);
    float* sc2 = (float*)alloc((size_t)NN * 4);
    float* sc3 = (float*)alloc((size_t)NN * 4);
    int*   deg = (int*)alloc((size_t)NN * 4);
    int*   offs   = (int*)alloc((size_t)(NN + 1) * 4);
    int*   cursor = (int*)alloc((size_t)NN * 4);
    int*   bsums  = (int*)alloc(512);
    int*   mode   = (int*)alloc(4);
    int*   srcs   = (int*)alloc((size_t)NE * 4);
    size_t fixed = off;

    auto mbytes = [](int cb) { return (size_t)NN * cb * 16; };
    int CB = 4;
    if      (ws_size >= fixed + 2 * mbytes(32) + 512) CB = 32;
    else if (ws_size >= fixed + 2 * mbytes(16) + 512) CB = 16;
    else if (ws_size >= fixed + 2 * mbytes(8)  + 512) CB = 8;
    unsigned char* MA = (unsigned char*)alloc(mbytes(CB));
    unsigned char* MB = (unsigned char*)alloc(mbytes(CB));

    // CSR build
    zero_kernel<<<(NN + 255) / 256, 256, 0, stream>>>(deg, NN);
    detect_kernel<<<1, 256, 0, stream>>>(ei, mode);
    count_kernel<<<(NE + 255) / 256, 256, 0, stream>>>(ei, deg, mode);
    int nb = (NN + 1023) / 1024;
    scan1_kernel<<<nb, 256, 0, stream>>>(deg, offs, bsums);
    scan2_kernel<<<1, 128, 0, stream>>>(bsums, nb);
    scan3_kernel<<<(NN + 255) / 256, 256, 0, stream>>>(offs, bsums, cursor);
    fill_kernel<<<(NE + 255) / 256, 256, 0, stream>>>(ei, cursor, srcs, mode);

    // node-wise MLPs (MFMA)
    phase1_kernel<<<1563, 256, 0, stream>>>(feat, Win, bin, Wq, bq, Wk, bk, Wv, bv,
                                            hopw, Qg, K0b, Vb, out);

    if (CB == 32) {
        hop64_kernel<true,  true ><<<25000, 256, 0, stream>>>(Qg, K0b, Vb, nullptr, MA, K1b, offs, srcs, hopw, 1, out);
        hop64_kernel<false, true ><<<25000, 256, 0, stream>>>(Qg, K1b, Vb, MA, MB, K2b, offs, srcs, hopw, 2, out);
        hop64_kernel<false, false><<<25000, 256, 0, stream>>>(Qg, K2b, Vb, MB, nullptr, nullptr, offs, srcs, hopw, 3, out);
    } else {
        kprop_kernel<<<12500, 256, 0, stream>>>(Qg, K0b, K1b, offs, srcs, hopw, 1, sc1);
        kprop_kernel<<<12500, 256, 0, stream>>>(Qg, K1b, K2b, offs, srcs, hopw, 2, sc2);
        kprop_kernel<<<12500, 256, 0, stream>>>(Qg, K2b, K3b, offs, srcs, hopw, 3, sc3);
        if      (CB == 16) run_chunks<16>(Qg, K0b, Vb, MA, MB, offs, srcs, sc1, sc2, sc3, out, stream);
        else if (CB == 8)  run_chunks<8> (Qg, K0b, Vb, MA, MB, offs, srcs, sc1, sc2, sc3, out, stream);
        else               run_chunks<4> (Qg, K0b, Vb, MA, MB, offs, srcs, sc1, sc2, sc3, out, stream);
    }
}